// Round 5
// baseline (216.716 us; speedup 1.0000x reference)
//
#include <hip/hip_runtime.h>

typedef __attribute__((ext_vector_type(8))) short short8;
typedef __attribute__((ext_vector_type(4))) float f32x4;

__device__ __forceinline__ unsigned short f2bf(float f) {
    union { float f; unsigned int i; } v; v.f = f;
    unsigned int x = v.i;
    return (unsigned short)((x + 0x7FFFu + ((x >> 16) & 1u)) >> 16); // RNE, finite inputs
}

// ---------------------------------------------------------------------------
// Convert the three fp32 512x512 weight matrices to bf16 for MFMA.
// 786432 elements; 384 blocks x 256 threads x 8 floats.
// ---------------------------------------------------------------------------
__global__ void convertW_kernel(const float* __restrict__ Wq,
                                const float* __restrict__ Wk,
                                const float* __restrict__ Wv,
                                unsigned short* __restrict__ Wqb,
                                unsigned short* __restrict__ Wkb,
                                unsigned short* __restrict__ Wvb)
{
    const int i = blockIdx.x * 256 + threadIdx.x;
    const int m = i >> 15;                          // 32768 threads per matrix
    const int o = (i & 32767) * 8;
    const float* src = (m == 0) ? Wq : (m == 1) ? Wk : Wv;
    unsigned short* dst = (m == 0) ? Wqb : (m == 1) ? Wkb : Wvb;
    float4 a = *(const float4*)(src + o);
    float4 b = *(const float4*)(src + o + 4);
    *(ushort4*)(dst + o)     = make_ushort4(f2bf(a.x), f2bf(a.y), f2bf(a.z), f2bf(a.w));
    *(ushort4*)(dst + o + 4) = make_ushort4(f2bf(b.x), f2bf(b.y), f2bf(b.z), f2bf(b.w));
}

// ---------------------------------------------------------------------------
// Per (b,c) plane of fp32 x (4096 pixels, 16 KB):
//   xsum[b][j][c] = sum of 16 consecutive flat pixels (group j)   (for Vsum)
//   xavg[b][n][c] = mean of 4x4 spatial block n = bh*16+bw        (for Q,K)
// grid = B*C = 4096 blocks, 256 threads; fp32 accumulate, bf16 stores.
// ---------------------------------------------------------------------------
__global__ void reduce_kernel(const float* __restrict__ x,
                              unsigned short* __restrict__ xavg,
                              unsigned short* __restrict__ xsum)
{
    const int plane = blockIdx.x;          // b*512 + c
    const int b = plane >> 9;
    const int c = plane & 511;
    const int t = threadIdx.x;             // t = flat group j

    const float4* p = (const float4*)(x + (size_t)plane * 4096) + t * 4;
    float4 a0 = p[0], a1 = p[1], a2 = p[2], a3 = p[3];
    float s0 = a0.x + a0.y + a0.z + a0.w;
    float s1 = a1.x + a1.y + a1.z + a1.w;
    float s2 = a2.x + a2.y + a2.z + a2.w;
    float s3 = a3.x + a3.y + a3.z + a3.w;

    xsum[((size_t)b * 256 + t) * 512 + c] = f2bf(s0 + s1 + s2 + s3);

    // partial sums of 4 pixels; linear idx (h*16 + colquad) == 4t+i
    __shared__ float part[1024];
    ((float4*)part)[t] = make_float4(s0, s1, s2, s3);
    __syncthreads();

    const int bh = t >> 4, bw = t & 15;    // spatial block n = t = bh*16+bw
    float m = (part[(bh * 4 + 0) * 16 + bw] + part[(bh * 4 + 1) * 16 + bw] +
               part[(bh * 4 + 2) * 16 + bw] + part[(bh * 4 + 3) * 16 + bw]) * 0.0625f;
    xavg[((size_t)b * 256 + t) * 512 + c] = f2bf(m);
}

// ---------------------------------------------------------------------------
// Batched NT GEMM via MFMA 16x16x32 bf16:  Y = X @ W^T (+ bias_mult * bias)
// One wave per 16x16 tile; fragments loaded directly from global (16B/lane).
// bias fp32. mode: 0 = bf16 store, 1 = bf16 transposed store, 2 = fp32 store.
// A frag: X[m=lane&15][k=quad*8+j]; B frag: W[n=lane&15][k=quad*8+j]
// D: col = lane&15 (N-dim), row = quad*4 + reg (M-dim).   [guide §3, m89/m91]
// ---------------------------------------------------------------------------
__global__ void gemm_nt_kernel(const unsigned short* __restrict__ X,
                               const unsigned short* __restrict__ W,
                               const float* __restrict__ bias,
                               void* __restrict__ Y,
                               int N, int Kd,
                               int ldX, int ldW, int ldY,
                               long sX, long sW, long sY,
                               float bias_mult, int mode)
{
    const int batch = blockIdx.y;
    const int wave = blockIdx.x * 4 + (threadIdx.x >> 6);
    const int tN = N >> 4;
    const int mt = wave / tN, nt = wave % tN;
    const int lane = threadIdx.x & 63;
    const int quad = lane >> 4, r16 = lane & 15;

    const unsigned short* xp = X + (size_t)batch * sX + (size_t)(mt * 16 + r16) * ldX + quad * 8;
    const unsigned short* wp = W + (size_t)batch * sW + (size_t)(nt * 16 + r16) * ldW + quad * 8;

    f32x4 acc = {0.f, 0.f, 0.f, 0.f};
    for (int k = 0; k < Kd; k += 32) {
        short8 a = *(const short8*)(xp + k);
        short8 b = *(const short8*)(wp + k);
        acc = __builtin_amdgcn_mfma_f32_16x16x32_bf16(a, b, acc, 0, 0, 0);
    }

    const int col = nt * 16 + r16;                 // N-dim
    const float bval = bias ? bias_mult * bias[col] : 0.f;
#pragma unroll
    for (int r = 0; r < 4; ++r) {
        const int row = mt * 16 + quad * 4 + r;    // M-dim
        const float v = acc[r] + bval;
        if (mode == 2) {
            ((float*)Y)[(size_t)batch * sY + (size_t)row * ldY + col] = v;
        } else if (mode == 1) {
            ((unsigned short*)Y)[(size_t)batch * sY + (size_t)col * ldY + row] = f2bf(v);
        } else {
            ((unsigned short*)Y)[(size_t)batch * sY + (size_t)row * ldY + col] = f2bf(v);
        }
    }
}

// ---------------------------------------------------------------------------
// Row softmax: rows of 256 fp32 scores -> bf16 probabilities. One wave/row.
// ---------------------------------------------------------------------------
__global__ void softmax_kernel(const float* __restrict__ S,
                               unsigned short* __restrict__ A, float scale)
{
    const int row = blockIdx.x * 4 + (threadIdx.x >> 6);
    const int lane = threadIdx.x & 63;
    const float* sp = S + (size_t)row * 256;
    float v[4];
#pragma unroll
    for (int i = 0; i < 4; ++i) v[i] = sp[lane + i * 64] * scale;
    float mx = fmaxf(fmaxf(v[0], v[1]), fmaxf(v[2], v[3]));
    for (int off = 32; off; off >>= 1) mx = fmaxf(mx, __shfl_xor(mx, off));
    float sum = 0.f;
#pragma unroll
    for (int i = 0; i < 4; ++i) { v[i] = __expf(v[i] - mx); sum += v[i]; }
    for (int off = 32; off; off >>= 1) sum += __shfl_xor(sum, off);
    const float inv = 1.f / sum;
    unsigned short* ap = A + (size_t)row * 256;
#pragma unroll
    for (int i = 0; i < 4; ++i) ap[lane + i * 64] = f2bf(v[i] * inv);
}

// ---------------------------------------------------------------------------
// Fused out_small = A @ VsT^T and 16x flat-pixel expansion into fp32 d_out.
// Per batch: M=256 (blocks n), N=512 (channels c), K=256. One wave per tile.
// acc element (row=n, col=c) broadcasts to out[b][c][16n..16n+16) (64 B).
// Reads ONLY d_ws (A, VsT); writes all of d_out.
// ---------------------------------------------------------------------------
__global__ void gemm_av_expand(const unsigned short* __restrict__ A,
                               const unsigned short* __restrict__ V,
                               float* __restrict__ out)
{
    const int bz = blockIdx.y;
    const int wave = blockIdx.x * 4 + (threadIdx.x >> 6);   // 0..511
    const int mt = wave >> 5, nt = wave & 31;               // tN = 32
    const int lane = threadIdx.x & 63;
    const int quad = lane >> 4, r16 = lane & 15;

    const unsigned short* ap = A + (size_t)bz * 65536  + (size_t)(mt * 16 + r16) * 256 + quad * 8;
    const unsigned short* vp = V + (size_t)bz * 131072 + (size_t)(nt * 16 + r16) * 256 + quad * 8;

    f32x4 acc = {0.f, 0.f, 0.f, 0.f};
    for (int k = 0; k < 256; k += 32) {
        short8 a = *(const short8*)(ap + k);
        short8 b = *(const short8*)(vp + k);
        acc = __builtin_amdgcn_mfma_f32_16x16x32_bf16(a, b, acc, 0, 0, 0);
    }

    const int c = nt * 16 + r16;                   // channel
    float* ob = out + ((size_t)(bz * 512 + c)) * 4096;
#pragma unroll
    for (int r = 0; r < 4; ++r) {
        const int n = mt * 16 + quad * 4 + r;      // block -> pixels [16n,16n+16)
        const float v = acc[r];
        float4 q = make_float4(v, v, v, v);
        float4* dst = (float4*)(ob + n * 16);
        dst[0] = q; dst[1] = q; dst[2] = q; dst[3] = q;
    }
}

extern "C" void kernel_launch(void* const* d_in, const int* in_sizes, int n_in,
                              void* d_out, int out_size, void* d_ws, size_t ws_size,
                              hipStream_t stream) {
    // All inputs fp32, output fp32 — per the reference file (R0-R4 bisect).
    const float* x  = (const float*)d_in[0];
    const float* Wq = (const float*)d_in[1];
    const float* bq = (const float*)d_in[2];
    const float* Wk = (const float*)d_in[3];
    const float* bk = (const float*)d_in[4];
    const float* Wv = (const float*)d_in[5];
    const float* bv = (const float*)d_in[6];
    float* out = (float*)d_out;

    // Early-lifetime scratch inside d_out (fp32 out = 67 MB; we use ~12 MB,
    // all dead before the final kernel rewrites d_out). Final kernel reads
    // only d_ws (3 MB): VsT + Amat.
    unsigned short* so   = (unsigned short*)d_out;
    unsigned short* Wqb  = so;                       // 262144 shorts
    unsigned short* Wkb  = Wqb + 262144;
    unsigned short* Wvb  = Wkb + 262144;
    unsigned short* xavg = Wvb + 262144;             // 1M shorts
    unsigned short* xsum = xavg + 1048576;           // 1M
    unsigned short* Q    = xsum + 1048576;           // 1M
    unsigned short* Km   = Q    + 1048576;           // 1M
    float*          Sc   = (float*)(Km + 1048576);   // 0.5M floats
    unsigned short* VsT  = (unsigned short*)d_ws;    // 1M shorts (2 MB)
    unsigned short* Amat = VsT + 1048576;            // 0.5M shorts (1 MB)

    // 0. fp32 -> bf16 weights
    convertW_kernel<<<384, 256, 0, stream>>>(Wq, Wk, Wv, Wqb, Wkb, Wvb);
    // 1. block means + flat-group sums
    reduce_kernel<<<4096, 256, 0, stream>>>(x, xavg, xsum);
    // 2. Q = xavg@Wq^T+bq ; K = xavg@Wk^T+bk  (M=2048 fused, N=512, K=512)
    gemm_nt_kernel<<<dim3(1024, 1), 256, 0, stream>>>(xavg, Wqb, bq, Q, 512, 512,
                                                      512, 512, 512, 0, 0, 0, 1.f, 0);
    gemm_nt_kernel<<<dim3(1024, 1), 256, 0, stream>>>(xavg, Wkb, bk, Km, 512, 512,
                                                      512, 512, 512, 0, 0, 0, 1.f, 0);
    // 3. VsT[c][m] = (xsum@Wv^T + 16*bv)^T per batch (M=256, N=512, K=512)
    gemm_nt_kernel<<<dim3(128, 8), 256, 0, stream>>>(xsum, Wvb, bv, VsT, 512, 512,
                                                     512, 512, 256,
                                                     131072, 0, 131072, 16.f, 1);
    // 4. Sc = Q @ K^T per batch, fp32 (M=256, N=256, K=512)
    gemm_nt_kernel<<<dim3(64, 8), 256, 0, stream>>>(Q, Km, nullptr, Sc, 256, 512,
                                                    512, 512, 256,
                                                    131072, 131072, 65536, 0.f, 2);
    // 5. A = softmax(Sc / sqrt(512)) rowwise -> bf16
    softmax_kernel<<<512, 256, 0, stream>>>(Sc, Amat, 0.044194173824159216f);
    // 6+7. out = expand16(A @ VsT^T) per batch, fp32 out
    gemm_av_expand<<<dim3(128, 8), 256, 0, stream>>>(Amat, VsT, out);
}

// Round 6
// 199.663 us; speedup vs baseline: 1.0854x; 1.0854x over previous
//
#include <hip/hip_runtime.h>

typedef __attribute__((ext_vector_type(8))) short short8;
typedef __attribute__((ext_vector_type(4))) float f32x4;

__device__ __forceinline__ unsigned short f2bf(float f) {
    union { float f; unsigned int i; } v; v.f = f;
    unsigned int x = v.i;
    return (unsigned short)((x + 0x7FFFu + ((x >> 16) & 1u)) >> 16); // RNE, finite inputs
}
__device__ __forceinline__ f32x4 mfma16(short8 a, short8 b, f32x4 c) {
    return __builtin_amdgcn_mfma_f32_16x16x32_bf16(a, b, c, 0, 0, 0);
}

// ---------------------------------------------------------------------------
// K1: fused input prep.
// Blocks 0..4095: per (b,c) plane of fp32 x -> xsum (group sums) + xavg
// (4x4 block means), bf16. Blocks 4096..4479: convert Wq|Wk|Wv fp32->bf16
// into the contiguous Wb buffer (Q rows 0..511, K rows 512..1023, V after).
// ---------------------------------------------------------------------------
__global__ void prep_kernel(const float* __restrict__ x,
                            const float* __restrict__ Wq,
                            const float* __restrict__ Wk,
                            const float* __restrict__ Wv,
                            unsigned short* __restrict__ xavg,
                            unsigned short* __restrict__ xsum,
                            unsigned short* __restrict__ Wb)
{
    const int blk = blockIdx.x;
    const int t = threadIdx.x;
    if (blk >= 4096) {                      // weight conversion
        const int i = (blk - 4096) * 256 + t;
        const int m = i >> 15;              // 32768 threads per matrix
        const int o = (i & 32767) * 8;
        const float* src = (m == 0) ? Wq : (m == 1) ? Wk : Wv;
        unsigned short* dst = Wb + m * 262144 + o;
        float4 a = *(const float4*)(src + o);
        float4 b = *(const float4*)(src + o + 4);
        *(ushort4*)(dst)     = make_ushort4(f2bf(a.x), f2bf(a.y), f2bf(a.z), f2bf(a.w));
        *(ushort4*)(dst + 4) = make_ushort4(f2bf(b.x), f2bf(b.y), f2bf(b.z), f2bf(b.w));
        return;
    }
    const int b = blk >> 9;                 // plane = b*512 + c
    const int c = blk & 511;

    const float4* p = (const float4*)(x + (size_t)blk * 4096) + t * 4;
    float4 a0 = p[0], a1 = p[1], a2 = p[2], a3 = p[3];
    float s0 = a0.x + a0.y + a0.z + a0.w;
    float s1 = a1.x + a1.y + a1.z + a1.w;
    float s2 = a2.x + a2.y + a2.z + a2.w;
    float s3 = a3.x + a3.y + a3.z + a3.w;

    xsum[((size_t)b * 256 + t) * 512 + c] = f2bf(s0 + s1 + s2 + s3);

    __shared__ float part[1024];
    ((float4*)part)[t] = make_float4(s0, s1, s2, s3);
    __syncthreads();

    const int bh = t >> 4, bw = t & 15;     // spatial block n = t
    float m = (part[(bh * 4 + 0) * 16 + bw] + part[(bh * 4 + 1) * 16 + bw] +
               part[(bh * 4 + 2) * 16 + bw] + part[(bh * 4 + 3) * 16 + bw]) * 0.0625f;
    xavg[((size_t)b * 256 + t) * 512 + c] = f2bf(m);
}

// ---------------------------------------------------------------------------
// K2: QK projection. QK[2048x1024] = xavg[2048x512] @ [Wq;Wk]^T + [bq;bk].
// One wave per 32x32 tile (2x2 of 16x16x32): 4 loads -> 4 MFMA per K-step.
// 2048 waves = 512 blocks.
// ---------------------------------------------------------------------------
__global__ void qk_gemm(const unsigned short* __restrict__ X,
                        const unsigned short* __restrict__ Wqk,
                        const float* __restrict__ bq,
                        const float* __restrict__ bk,
                        unsigned short* __restrict__ QK)
{
    const int wave = blockIdx.x * 4 + (threadIdx.x >> 6);
    const int mt2 = wave >> 5, nt2 = wave & 31;
    const int lane = threadIdx.x & 63, quad = lane >> 4, r16 = lane & 15;
    const unsigned short* xp0 = X + (size_t)(mt2 * 32 + r16) * 512 + quad * 8;
    const unsigned short* xp1 = xp0 + 16 * 512;
    const unsigned short* wp0 = Wqk + (size_t)(nt2 * 32 + r16) * 512 + quad * 8;
    const unsigned short* wp1 = wp0 + 16 * 512;

    f32x4 acc00 = {0,0,0,0}, acc01 = acc00, acc10 = acc00, acc11 = acc00;
#pragma unroll 4
    for (int k = 0; k < 512; k += 32) {
        short8 a0 = *(const short8*)(xp0 + k);
        short8 a1 = *(const short8*)(xp1 + k);
        short8 b0 = *(const short8*)(wp0 + k);
        short8 b1 = *(const short8*)(wp1 + k);
        acc00 = mfma16(a0, b0, acc00);
        acc01 = mfma16(a0, b1, acc01);
        acc10 = mfma16(a1, b0, acc10);
        acc11 = mfma16(a1, b1, acc11);
    }
    const int c0 = nt2 * 32 + r16, c1 = c0 + 16;
    const float bias0 = (c0 < 512) ? bq[c0] : bk[c0 - 512];
    const float bias1 = (c1 < 512) ? bq[c1] : bk[c1 - 512];
    const int row0 = mt2 * 32 + quad * 4;
#pragma unroll
    for (int r = 0; r < 4; ++r) {
        QK[(size_t)(row0 + r) * 1024 + c0]      = f2bf(acc00[r] + bias0);
        QK[(size_t)(row0 + r) * 1024 + c1]      = f2bf(acc01[r] + bias1);
        QK[(size_t)(row0 + 16 + r) * 1024 + c0] = f2bf(acc10[r] + bias0);
        QK[(size_t)(row0 + 16 + r) * 1024 + c1] = f2bf(acc11[r] + bias1);
    }
}

// ---------------------------------------------------------------------------
// K3: Vsum projection, transposed store. Per batch:
// VsT[c][m] = sum_k xsum[m][k]*Wv[c][k] + 16*bv[c].  32x32/wave, 128 waves/b.
// ---------------------------------------------------------------------------
__global__ void v_gemm(const unsigned short* __restrict__ xsum,
                       const unsigned short* __restrict__ Wvb,
                       const float* __restrict__ bv,
                       unsigned short* __restrict__ VsT)
{
    const int b = blockIdx.y;
    const int wave = blockIdx.x * 4 + (threadIdx.x >> 6);   // 0..127
    const int mt2 = wave >> 4, nt2 = wave & 15;
    const int lane = threadIdx.x & 63, quad = lane >> 4, r16 = lane & 15;
    const unsigned short* xp0 = xsum + (size_t)b * 131072 + (size_t)(mt2 * 32 + r16) * 512 + quad * 8;
    const unsigned short* xp1 = xp0 + 16 * 512;
    const unsigned short* wp0 = Wvb + (size_t)(nt2 * 32 + r16) * 512 + quad * 8;
    const unsigned short* wp1 = wp0 + 16 * 512;

    f32x4 acc00 = {0,0,0,0}, acc01 = acc00, acc10 = acc00, acc11 = acc00;
#pragma unroll 4
    for (int k = 0; k < 512; k += 32) {
        short8 a0 = *(const short8*)(xp0 + k);
        short8 a1 = *(const short8*)(xp1 + k);
        short8 b0 = *(const short8*)(wp0 + k);
        short8 b1 = *(const short8*)(wp1 + k);
        acc00 = mfma16(a0, b0, acc00);
        acc01 = mfma16(a0, b1, acc01);
        acc10 = mfma16(a1, b0, acc10);
        acc11 = mfma16(a1, b1, acc11);
    }
    const int c0 = nt2 * 32 + r16, c1 = c0 + 16;
    const float bias0 = 16.f * bv[c0], bias1 = 16.f * bv[c1];
    unsigned short* vb = VsT + (size_t)b * 131072;
    const int m0 = mt2 * 32 + quad * 4;
#pragma unroll
    for (int r = 0; r < 4; ++r) {
        vb[(size_t)c0 * 256 + m0 + r]      = f2bf(acc00[r] + bias0);
        vb[(size_t)c1 * 256 + m0 + r]      = f2bf(acc01[r] + bias1);
        vb[(size_t)c0 * 256 + m0 + 16 + r] = f2bf(acc10[r] + bias0);
        vb[(size_t)c1 * 256 + m0 + 16 + r] = f2bf(acc11[r] + bias1);
    }
}

// ---------------------------------------------------------------------------
// K4: fused scores + softmax. Block = (strip of 32 score rows) x (batch).
// 4 waves compute the 32x256 fp32 score strip (QK^T, K=512) into LDS,
// then 256 threads softmax rows (thread: row t/8, 32 cols) -> bf16 A.
// ---------------------------------------------------------------------------
__global__ void score_softmax(const unsigned short* __restrict__ QK,
                              unsigned short* __restrict__ Amat)
{
    __shared__ float S[32][257];
    const int b = blockIdx.y, strip = blockIdx.x;
    const int w = threadIdx.x >> 6, lane = threadIdx.x & 63;
    const int quad = lane >> 4, r16 = lane & 15;
    const unsigned short* qp0 = QK + (size_t)(b * 256 + strip * 32 + r16) * 1024 + quad * 8;
    const unsigned short* qp1 = qp0 + 16 * 1024;

#pragma unroll
    for (int g = 0; g < 2; ++g) {
        const int ct = w * 2 + g;                           // col tile 0..7
        const unsigned short* kp0 = QK + (size_t)(b * 256 + ct * 32 + r16) * 1024 + 512 + quad * 8;
        const unsigned short* kp1 = kp0 + 16 * 1024;
        f32x4 acc00 = {0,0,0,0}, acc01 = acc00, acc10 = acc00, acc11 = acc00;
#pragma unroll 4
        for (int k = 0; k < 512; k += 32) {
            short8 a0 = *(const short8*)(qp0 + k);
            short8 a1 = *(const short8*)(qp1 + k);
            short8 b0 = *(const short8*)(kp0 + k);
            short8 b1 = *(const short8*)(kp1 + k);
            acc00 = mfma16(a0, b0, acc00);
            acc01 = mfma16(a0, b1, acc01);
            acc10 = mfma16(a1, b0, acc10);
            acc11 = mfma16(a1, b1, acc11);
        }
        const int col0 = ct * 32 + r16;
#pragma unroll
        for (int r = 0; r < 4; ++r) {
            S[quad * 4 + r][col0]           = acc00[r];
            S[quad * 4 + r][col0 + 16]      = acc01[r];
            S[quad * 4 + 16 + r][col0]      = acc10[r];
            S[quad * 4 + 16 + r][col0 + 16] = acc11[r];
        }
    }
    __syncthreads();

    const int t = threadIdx.x;
    const int r = t >> 3, seg = t & 7;      // row r, cols seg*32..+32
    float v[32];
    float mx = -3.4e38f;
#pragma unroll
    for (int j = 0; j < 32; ++j) {
        v[j] = S[r][seg * 32 + j] * 0.044194173824159216f;
        mx = fmaxf(mx, v[j]);
    }
    mx = fmaxf(mx, __shfl_xor(mx, 1));
    mx = fmaxf(mx, __shfl_xor(mx, 2));
    mx = fmaxf(mx, __shfl_xor(mx, 4));
    float sum = 0.f;
#pragma unroll
    for (int j = 0; j < 32; ++j) { v[j] = __expf(v[j] - mx); sum += v[j]; }
    sum += __shfl_xor(sum, 1);
    sum += __shfl_xor(sum, 2);
    sum += __shfl_xor(sum, 4);
    const float inv = 1.f / sum;
    unsigned short* ap = Amat + (size_t)b * 65536 + (size_t)(strip * 32 + r) * 256 + seg * 32;
#pragma unroll
    for (int j = 0; j < 32; j += 4)
        *(ushort4*)(ap + j) = make_ushort4(f2bf(v[j] * inv), f2bf(v[j + 1] * inv),
                                           f2bf(v[j + 2] * inv), f2bf(v[j + 3] * inv));
}

// ---------------------------------------------------------------------------
// K5: fused out_small = A @ VsT^T + 16x flat-pixel expansion into fp32 d_out.
// 32x32/wave, K=256; acc(row=n, col=c) broadcasts to out[b][c][16n..16n+16).
// Reads ONLY d_ws; writes all of d_out.
// ---------------------------------------------------------------------------
__global__ void av_expand(const unsigned short* __restrict__ Amat,
                          const unsigned short* __restrict__ VsT,
                          float* __restrict__ out)
{
    const int b = blockIdx.y;
    const int wave = blockIdx.x * 4 + (threadIdx.x >> 6);   // 0..127
    const int mt2 = wave >> 4, nt2 = wave & 15;
    const int lane = threadIdx.x & 63, quad = lane >> 4, r16 = lane & 15;
    const unsigned short* ap0 = Amat + (size_t)b * 65536 + (size_t)(mt2 * 32 + r16) * 256 + quad * 8;
    const unsigned short* ap1 = ap0 + 16 * 256;
    const unsigned short* vp0 = VsT + (size_t)b * 131072 + (size_t)(nt2 * 32 + r16) * 256 + quad * 8;
    const unsigned short* vp1 = vp0 + 16 * 256;

    f32x4 acc00 = {0,0,0,0}, acc01 = acc00, acc10 = acc00, acc11 = acc00;
#pragma unroll 4
    for (int k = 0; k < 256; k += 32) {
        short8 a0 = *(const short8*)(ap0 + k);
        short8 a1 = *(const short8*)(ap1 + k);
        short8 b0 = *(const short8*)(vp0 + k);
        short8 b1 = *(const short8*)(vp1 + k);
        acc00 = mfma16(a0, b0, acc00);
        acc01 = mfma16(a0, b1, acc01);
        acc10 = mfma16(a1, b0, acc10);
        acc11 = mfma16(a1, b1, acc11);
    }
    const int c0 = nt2 * 32 + r16, c1 = c0 + 16;
    float* ob0 = out + (size_t)(b * 512 + c0) * 4096;
    float* ob1 = out + (size_t)(b * 512 + c1) * 4096;
    const int n0 = mt2 * 32 + quad * 4;
#pragma unroll
    for (int r = 0; r < 4; ++r) {
        float4 q;
        float4* d;
        q = make_float4(acc00[r], acc00[r], acc00[r], acc00[r]);
        d = (float4*)(ob0 + (n0 + r) * 16);      d[0] = q; d[1] = q; d[2] = q; d[3] = q;
        q = make_float4(acc01[r], acc01[r], acc01[r], acc01[r]);
        d = (float4*)(ob1 + (n0 + r) * 16);      d[0] = q; d[1] = q; d[2] = q; d[3] = q;
        q = make_float4(acc10[r], acc10[r], acc10[r], acc10[r]);
        d = (float4*)(ob0 + (n0 + 16 + r) * 16); d[0] = q; d[1] = q; d[2] = q; d[3] = q;
        q = make_float4(acc11[r], acc11[r], acc11[r], acc11[r]);
        d = (float4*)(ob1 + (n0 + 16 + r) * 16); d[0] = q; d[1] = q; d[2] = q; d[3] = q;
    }
}

extern "C" void kernel_launch(void* const* d_in, const int* in_sizes, int n_in,
                              void* d_out, int out_size, void* d_ws, size_t ws_size,
                              hipStream_t stream) {
    const float* x  = (const float*)d_in[0];
    const float* Wq = (const float*)d_in[1];
    const float* bq = (const float*)d_in[2];
    const float* Wk = (const float*)d_in[3];
    const float* bk = (const float*)d_in[4];
    const float* Wv = (const float*)d_in[5];
    const float* bv = (const float*)d_in[6];
    float* out = (float*)d_out;

    // Early-lifetime scratch inside d_out (~10 MB of 67 MB; all dead before
    // K5 rewrites d_out). K5 reads only d_ws (3 MB).
    unsigned short* so   = (unsigned short*)d_out;
    unsigned short* Wb   = so;                       // 786432 shorts (Wq|Wk|Wv)
    unsigned short* xavg = Wb + 786432;              // 1048576
    unsigned short* xsum = xavg + 1048576;           // 1048576
    unsigned short* QK   = xsum + 1048576;           // 2097152 (2048x1024)
    unsigned short* VsT  = (unsigned short*)d_ws;    // 1048576 (8 x 512x256)
    unsigned short* Amat = VsT + 1048576;            // 524288  (8 x 256x256)

    // K1: reduce planes (4096 blocks) + weight convert (384 blocks)
    prep_kernel<<<4480, 256, 0, stream>>>(x, Wq, Wk, Wv, xavg, xsum, Wb);
    // K2: QK = xavg @ [Wq;Wk]^T + [bq;bk]   (M=2048, N=1024, K=512)
    qk_gemm<<<512, 256, 0, stream>>>(xavg, Wb, bq, bk, QK);
    // K3: VsT = (xsum @ Wv^T + 16*bv)^T per batch (M=256, N=512, K=512)
    v_gemm<<<dim3(32, 8), 256, 0, stream>>>(xsum, Wb + 524288, bv, VsT);
    // K4: A = softmax(Q K^T / sqrt(512)) per batch, fused strip softmax
    score_softmax<<<dim3(8, 8), 256, 0, stream>>>(QK, Amat);
    // K5: out = expand16(A @ Vsum) per batch, fp32
    av_expand<<<dim3(32, 8), 256, 0, stream>>>(Amat, VsT, out);
}

// Round 7
// 193.211 us; speedup vs baseline: 1.1217x; 1.0334x over previous
//
#include <hip/hip_runtime.h>

typedef __attribute__((ext_vector_type(8))) short short8;
typedef __attribute__((ext_vector_type(4))) float f32x4;

__device__ __forceinline__ unsigned short f2bf(float f) {
    union { float f; unsigned int i; } v; v.f = f;
    unsigned int x = v.i;
    return (unsigned short)((x + 0x7FFFu + ((x >> 16) & 1u)) >> 16); // RNE, finite inputs
}
__device__ __forceinline__ f32x4 mfma16(short8 a, short8 b, f32x4 c) {
    return __builtin_amdgcn_mfma_f32_16x16x32_bf16(a, b, c, 0, 0, 0);
}

// ---------------------------------------------------------------------------
// K1: fused input prep.
// Blocks 0..4095: per (b,c) plane of fp32 x -> xsum (16-pixel group sums) +
// xavg (4x4 block means), bf16. Blocks 4096..4479: Wq|Wk|Wv fp32->bf16 into
// contiguous Wb (Q rows 0..511, K rows 512..1023, V rows 1024..1535).
// ---------------------------------------------------------------------------
__global__ void prep_kernel(const float* __restrict__ x,
                            const float* __restrict__ Wq,
                            const float* __restrict__ Wk,
                            const float* __restrict__ Wv,
                            unsigned short* __restrict__ xavg,
                            unsigned short* __restrict__ xsum,
                            unsigned short* __restrict__ Wb)
{
    const int blk = blockIdx.x;
    const int t = threadIdx.x;
    if (blk >= 4096) {                      // weight conversion
        const int i = (blk - 4096) * 256 + t;
        const int m = i >> 15;              // 32768 threads per matrix
        const int o = (i & 32767) * 8;
        const float* src = (m == 0) ? Wq : (m == 1) ? Wk : Wv;
        unsigned short* dst = Wb + m * 262144 + o;
        float4 a = *(const float4*)(src + o);
        float4 b = *(const float4*)(src + o + 4);
        *(ushort4*)(dst)     = make_ushort4(f2bf(a.x), f2bf(a.y), f2bf(a.z), f2bf(a.w));
        *(ushort4*)(dst + 4) = make_ushort4(f2bf(b.x), f2bf(b.y), f2bf(b.z), f2bf(b.w));
        return;
    }
    const int b = blk >> 9;                 // plane = b*512 + c
    const int c = blk & 511;

    const float4* p = (const float4*)(x + (size_t)blk * 4096) + t * 4;
    float4 a0 = p[0], a1 = p[1], a2 = p[2], a3 = p[3];
    float s0 = a0.x + a0.y + a0.z + a0.w;
    float s1 = a1.x + a1.y + a1.z + a1.w;
    float s2 = a2.x + a2.y + a2.z + a2.w;
    float s3 = a3.x + a3.y + a3.z + a3.w;

    xsum[((size_t)b * 256 + t) * 512 + c] = f2bf(s0 + s1 + s2 + s3);

    __shared__ float part[1024];
    ((float4*)part)[t] = make_float4(s0, s1, s2, s3);
    __syncthreads();

    const int bh = t >> 4, bw = t & 15;     // spatial block n = t
    float m = (part[(bh * 4 + 0) * 16 + bw] + part[(bh * 4 + 1) * 16 + bw] +
               part[(bh * 4 + 2) * 16 + bw] + part[(bh * 4 + 3) * 16 + bw]) * 0.0625f;
    xavg[((size_t)b * 256 + t) * 512 + c] = f2bf(m);
}

// ---------------------------------------------------------------------------
// K2: joint projection kernel (768 blocks).
// Blocks 0..511:  QK[2048x1024] = xavg @ [Wq;Wk]^T + [bq;bk], 32x32 tile/wave.
// Blocks 512..767: VsT[b][c][m] = (xsum[b] @ Wv^T + 16*bv)^T, 32x32 tile/wave.
// A frag: X[m=lane&15][k=quad*8+j]; B frag: W[n=lane&15][k=quad*8+j]
// D: col = lane&15 (N), row = quad*4+reg (M).            [guide §3, m89/m91]
// ---------------------------------------------------------------------------
__global__ void proj_gemm(const unsigned short* __restrict__ xavg,
                          const unsigned short* __restrict__ xsum,
                          const unsigned short* __restrict__ Wb,
                          const float* __restrict__ bq,
                          const float* __restrict__ bk,
                          const float* __restrict__ bv,
                          unsigned short* __restrict__ QK,
                          unsigned short* __restrict__ VsT)
{
    const int blk = blockIdx.x;
    const int lane = threadIdx.x & 63, quad = lane >> 4, r16 = lane & 15;
    const int w = threadIdx.x >> 6;

    if (blk < 512) {                        // ---- QK projection ----
        const int wave = blk * 4 + w;       // 0..2047
        const int mt2 = wave >> 5, nt2 = wave & 31;
        const unsigned short* xp0 = xavg + (size_t)(mt2 * 32 + r16) * 512 + quad * 8;
        const unsigned short* xp1 = xp0 + 16 * 512;
        const unsigned short* wp0 = Wb + (size_t)(nt2 * 32 + r16) * 512 + quad * 8;
        const unsigned short* wp1 = wp0 + 16 * 512;

        f32x4 acc00 = {0,0,0,0}, acc01 = acc00, acc10 = acc00, acc11 = acc00;
#pragma unroll 4
        for (int k = 0; k < 512; k += 32) {
            short8 a0 = *(const short8*)(xp0 + k);
            short8 a1 = *(const short8*)(xp1 + k);
            short8 b0 = *(const short8*)(wp0 + k);
            short8 b1 = *(const short8*)(wp1 + k);
            acc00 = mfma16(a0, b0, acc00);
            acc01 = mfma16(a0, b1, acc01);
            acc10 = mfma16(a1, b0, acc10);
            acc11 = mfma16(a1, b1, acc11);
        }
        const int c0 = nt2 * 32 + r16, c1 = c0 + 16;
        const float bias0 = (c0 < 512) ? bq[c0] : bk[c0 - 512];
        const float bias1 = (c1 < 512) ? bq[c1] : bk[c1 - 512];
        const int row0 = mt2 * 32 + quad * 4;
#pragma unroll
        for (int r = 0; r < 4; ++r) {
            QK[(size_t)(row0 + r) * 1024 + c0]      = f2bf(acc00[r] + bias0);
            QK[(size_t)(row0 + r) * 1024 + c1]      = f2bf(acc01[r] + bias1);
            QK[(size_t)(row0 + 16 + r) * 1024 + c0] = f2bf(acc10[r] + bias0);
            QK[(size_t)(row0 + 16 + r) * 1024 + c1] = f2bf(acc11[r] + bias1);
        }
    } else {                                // ---- V projection (transposed) ----
        const int vblk = blk - 512;         // 0..255
        const int b = vblk >> 5;
        const int wave = (vblk & 31) * 4 + w;   // 0..127
        const int mt2 = wave >> 4, nt2 = wave & 15;
        const unsigned short* xp0 = xsum + (size_t)b * 131072 + (size_t)(mt2 * 32 + r16) * 512 + quad * 8;
        const unsigned short* xp1 = xp0 + 16 * 512;
        const unsigned short* wp0 = Wb + 524288 + (size_t)(nt2 * 32 + r16) * 512 + quad * 8;
        const unsigned short* wp1 = wp0 + 16 * 512;

        f32x4 acc00 = {0,0,0,0}, acc01 = acc00, acc10 = acc00, acc11 = acc00;
#pragma unroll 4
        for (int k = 0; k < 512; k += 32) {
            short8 a0 = *(const short8*)(xp0 + k);
            short8 a1 = *(const short8*)(xp1 + k);
            short8 b0 = *(const short8*)(wp0 + k);
            short8 b1 = *(const short8*)(wp1 + k);
            acc00 = mfma16(a0, b0, acc00);
            acc01 = mfma16(a0, b1, acc01);
            acc10 = mfma16(a1, b0, acc10);
            acc11 = mfma16(a1, b1, acc11);
        }
        const int c0 = nt2 * 32 + r16, c1 = c0 + 16;
        const float bias0 = 16.f * bv[c0], bias1 = 16.f * bv[c1];
        unsigned short* vb = VsT + (size_t)b * 131072;
        const int m0 = mt2 * 32 + quad * 4;
#pragma unroll
        for (int r = 0; r < 4; ++r) {
            vb[(size_t)c0 * 256 + m0 + r]      = f2bf(acc00[r] + bias0);
            vb[(size_t)c1 * 256 + m0 + r]      = f2bf(acc01[r] + bias1);
            vb[(size_t)c0 * 256 + m0 + 16 + r] = f2bf(acc10[r] + bias0);
            vb[(size_t)c1 * 256 + m0 + 16 + r] = f2bf(acc11[r] + bias1);
        }
    }
}

// ---------------------------------------------------------------------------
// K3: fused scores + softmax + (A @ Vsum) + 16x pixel expansion.
// Block = (strip of 32 A-rows, c-quarter of 128 channels, batch).
// Phase A: 4 waves compute the 32x256 fp32 score strip (K=512) into LDS
//          (duplicated across the 4 c-quarter siblings - cheap MFMA).
// Phase B: softmax rows -> bf16 A in LDS (row stride 264 = +16B pad; 16-lane
//          b128 reads then alias banks only 2-way, which is free [m136]).
// Phase C: each wave computes out_small[32 x 32c] = A_strip @ Vsum (K=256,
//          A-frags from LDS, V-frags from global VsT) and broadcasts each
//          element to its 16 flat pixels in d_out.
// Reads only d_ws; d_out written exactly once.
// ---------------------------------------------------------------------------
__global__ void attn_out(const unsigned short* __restrict__ QK,
                         const unsigned short* __restrict__ VsT,
                         float* __restrict__ out)
{
    __shared__ float S[32][257];
    __shared__ unsigned short Abf[32 * 264];
    const int b = blockIdx.y;
    const int strip = blockIdx.x >> 2;      // 0..7
    const int cq = blockIdx.x & 3;          // 0..3
    const int w = threadIdx.x >> 6, lane = threadIdx.x & 63;
    const int quad = lane >> 4, r16 = lane & 15;

    // ---- Phase A: scores (32 rows x 256 cols), K = 512 ----
    const unsigned short* qp0 = QK + (size_t)(b * 256 + strip * 32 + r16) * 1024 + quad * 8;
    const unsigned short* qp1 = qp0 + 16 * 1024;
#pragma unroll
    for (int g = 0; g < 2; ++g) {
        const int ct = w * 2 + g;           // col tile 0..7
        const unsigned short* kp0 = QK + (size_t)(b * 256 + ct * 32 + r16) * 1024 + 512 + quad * 8;
        const unsigned short* kp1 = kp0 + 16 * 1024;
        f32x4 acc00 = {0,0,0,0}, acc01 = acc00, acc10 = acc00, acc11 = acc00;
#pragma unroll 4
        for (int k = 0; k < 512; k += 32) {
            short8 a0 = *(const short8*)(qp0 + k);
            short8 a1 = *(const short8*)(qp1 + k);
            short8 b0 = *(const short8*)(kp0 + k);
            short8 b1 = *(const short8*)(kp1 + k);
            acc00 = mfma16(a0, b0, acc00);
            acc01 = mfma16(a0, b1, acc01);
            acc10 = mfma16(a1, b0, acc10);
            acc11 = mfma16(a1, b1, acc11);
        }
        const int col0 = ct * 32 + r16;
#pragma unroll
        for (int r = 0; r < 4; ++r) {
            S[quad * 4 + r][col0]           = acc00[r];
            S[quad * 4 + r][col0 + 16]      = acc01[r];
            S[quad * 4 + 16 + r][col0]      = acc10[r];
            S[quad * 4 + 16 + r][col0 + 16] = acc11[r];
        }
    }
    __syncthreads();

    // ---- Phase B: softmax rows -> bf16 A (LDS) ----
    {
        const int t = threadIdx.x;
        const int r = t >> 3, seg = t & 7;  // row r, cols seg*32..+32
        float v[32];
        float mx = -3.4e38f;
#pragma unroll
        for (int j = 0; j < 32; ++j) {
            v[j] = S[r][seg * 32 + j] * 0.044194173824159216f;
            mx = fmaxf(mx, v[j]);
        }
        mx = fmaxf(mx, __shfl_xor(mx, 1));
        mx = fmaxf(mx, __shfl_xor(mx, 2));
        mx = fmaxf(mx, __shfl_xor(mx, 4));
        float sum = 0.f;
#pragma unroll
        for (int j = 0; j < 32; ++j) { v[j] = __expf(v[j] - mx); sum += v[j]; }
        sum += __shfl_xor(sum, 1);
        sum += __shfl_xor(sum, 2);
        sum += __shfl_xor(sum, 4);
        const float inv = 1.f / sum;
        unsigned short* ap = Abf + r * 264 + seg * 32;
#pragma unroll
        for (int j = 0; j < 32; j += 4)
            *(ushort4*)(ap + j) = make_ushort4(f2bf(v[j] * inv), f2bf(v[j + 1] * inv),
                                               f2bf(v[j + 2] * inv), f2bf(v[j + 3] * inv));
    }
    __syncthreads();

    // ---- Phase C: out_small = A_strip @ Vsum, 32x32 per wave, + expand ----
    const int cbase = cq * 128 + w * 32;    // this wave's 32 channels
    const unsigned short* ap0 = Abf + r16 * 264 + quad * 8;
    const unsigned short* ap1 = ap0 + 16 * 264;
    const unsigned short* vp0 = VsT + (size_t)b * 131072 + (size_t)(cbase + r16) * 256 + quad * 8;
    const unsigned short* vp1 = vp0 + 16 * 256;

    f32x4 acc00 = {0,0,0,0}, acc01 = acc00, acc10 = acc00, acc11 = acc00;
#pragma unroll 4
    for (int k = 0; k < 256; k += 32) {
        short8 a0 = *(const short8*)(ap0 + k);
        short8 a1 = *(const short8*)(ap1 + k);
        short8 b0 = *(const short8*)(vp0 + k);
        short8 b1 = *(const short8*)(vp1 + k);
        acc00 = mfma16(a0, b0, acc00);
        acc01 = mfma16(a0, b1, acc01);
        acc10 = mfma16(a1, b0, acc10);
        acc11 = mfma16(a1, b1, acc11);
    }
    const int c0 = cbase + r16, c1 = c0 + 16;
    float* ob0 = out + (size_t)(b * 512 + c0) * 4096;
    float* ob1 = out + (size_t)(b * 512 + c1) * 4096;
    const int n0 = strip * 32 + quad * 4;
#pragma unroll
    for (int r = 0; r < 4; ++r) {
        float4 q;
        float4* d;
        q = make_float4(acc00[r], acc00[r], acc00[r], acc00[r]);
        d = (float4*)(ob0 + (n0 + r) * 16);      d[0] = q; d[1] = q; d[2] = q; d[3] = q;
        q = make_float4(acc01[r], acc01[r], acc01[r], acc01[r]);
        d = (float4*)(ob1 + (n0 + r) * 16);      d[0] = q; d[1] = q; d[2] = q; d[3] = q;
        q = make_float4(acc10[r], acc10[r], acc10[r], acc10[r]);
        d = (float4*)(ob0 + (n0 + 16 + r) * 16); d[0] = q; d[1] = q; d[2] = q; d[3] = q;
        q = make_float4(acc11[r], acc11[r], acc11[r], acc11[r]);
        d = (float4*)(ob1 + (n0 + 16 + r) * 16); d[0] = q; d[1] = q; d[2] = q; d[3] = q;
    }
}

extern "C" void kernel_launch(void* const* d_in, const int* in_sizes, int n_in,
                              void* d_out, int out_size, void* d_ws, size_t ws_size,
                              hipStream_t stream) {
    const float* x  = (const float*)d_in[0];
    const float* Wq = (const float*)d_in[1];
    const float* bq = (const float*)d_in[2];
    const float* Wk = (const float*)d_in[3];
    const float* bk = (const float*)d_in[4];
    const float* Wv = (const float*)d_in[5];
    const float* bv = (const float*)d_in[6];
    float* out = (float*)d_out;

    // All scratch in d_ws (11.5 MB); fully written before read each call.
    // d_out is written exactly once (by attn_out).
    unsigned short* Wb   = (unsigned short*)d_ws;    // 786432 shorts (Wq|Wk|Wv)
    unsigned short* xavg = Wb + 786432;              // 1048576
    unsigned short* xsum = xavg + 1048576;           // 1048576
    unsigned short* QK   = xsum + 1048576;           // 2097152 (2048x1024)
    unsigned short* VsT  = QK + 2097152;             // 1048576 (8 x 512x256)

    // K1: plane reductions (4096 blocks) + weight convert (384 blocks)
    prep_kernel<<<4480, 256, 0, stream>>>(x, Wq, Wk, Wv, xavg, xsum, Wb);
    // K2: QK = xavg @ [Wq;Wk]^T + bias  AND  VsT = (xsum @ Wv^T + 16*bv)^T
    proj_gemm<<<768, 256, 0, stream>>>(xavg, xsum, Wb, bq, bk, bv, QK, VsT);
    // K3: per (strip, c-quarter, batch): scores+softmax+AV+expand -> d_out
    attn_out<<<dim3(32, 8), 256, 0, stream>>>(QK, VsT, out);
}

// Round 8
// 192.987 us; speedup vs baseline: 1.1230x; 1.0012x over previous
//
#include <hip/hip_runtime.h>

typedef __attribute__((ext_vector_type(8))) short short8;
typedef __attribute__((ext_vector_type(4))) float f32x4;

__device__ __forceinline__ unsigned short f2bf(float f) {
    union { float f; unsigned int i; } v; v.f = f;
    unsigned int x = v.i;
    return (unsigned short)((x + 0x7FFFu + ((x >> 16) & 1u)) >> 16); // RNE, finite inputs
}
__device__ __forceinline__ f32x4 mfma16(short8 a, short8 b, f32x4 c) {
    return __builtin_amdgcn_mfma_f32_16x16x32_bf16(a, b, c, 0, 0, 0);
}

// ---------------------------------------------------------------------------
// K1: fused input prep.
// Blocks 0..4095: per (b,c) plane of fp32 x -> xsum (16-pixel group sums) +
// xavg (4x4 block means), bf16. Blocks 4096..4479: Wq|Wk|Wv fp32->bf16 into
// contiguous Wb (Q rows 0..511, K rows 512..1023, V rows 1024..1535).
// ---------------------------------------------------------------------------
__global__ void prep_kernel(const float* __restrict__ x,
                            const float* __restrict__ Wq,
                            const float* __restrict__ Wk,
                            const float* __restrict__ Wv,
                            unsigned short* __restrict__ xavg,
                            unsigned short* __restrict__ xsum,
                            unsigned short* __restrict__ Wb)
{
    const int blk = blockIdx.x;
    const int t = threadIdx.x;
    if (blk >= 4096) {                      // weight conversion
        const int i = (blk - 4096) * 256 + t;
        const int m = i >> 15;              // 32768 threads per matrix
        const int o = (i & 32767) * 8;
        const float* src = (m == 0) ? Wq : (m == 1) ? Wk : Wv;
        unsigned short* dst = Wb + m * 262144 + o;
        float4 a = *(const float4*)(src + o);
        float4 b = *(const float4*)(src + o + 4);
        *(ushort4*)(dst)     = make_ushort4(f2bf(a.x), f2bf(a.y), f2bf(a.z), f2bf(a.w));
        *(ushort4*)(dst + 4) = make_ushort4(f2bf(b.x), f2bf(b.y), f2bf(b.z), f2bf(b.w));
        return;
    }
    const int b = blk >> 9;                 // plane = b*512 + c
    const int c = blk & 511;

    const float4* p = (const float4*)(x + (size_t)blk * 4096) + t * 4;
    float4 a0 = p[0], a1 = p[1], a2 = p[2], a3 = p[3];
    float s0 = a0.x + a0.y + a0.z + a0.w;
    float s1 = a1.x + a1.y + a1.z + a1.w;
    float s2 = a2.x + a2.y + a2.z + a2.w;
    float s3 = a3.x + a3.y + a3.z + a3.w;

    xsum[((size_t)b * 256 + t) * 512 + c] = f2bf(s0 + s1 + s2 + s3);

    __shared__ float part[1024];
    ((float4*)part)[t] = make_float4(s0, s1, s2, s3);
    __syncthreads();

    const int bh = t >> 4, bw = t & 15;     // spatial block n = t
    float m = (part[(bh * 4 + 0) * 16 + bw] + part[(bh * 4 + 1) * 16 + bw] +
               part[(bh * 4 + 2) * 16 + bw] + part[(bh * 4 + 3) * 16 + bw]) * 0.0625f;
    xavg[((size_t)b * 256 + t) * 512 + c] = f2bf(m);
}

// ---------------------------------------------------------------------------
// K2: joint projection kernel (768 blocks).
// Blocks 0..511:  QK[2048x1024] = xavg @ [Wq;Wk]^T + [bq;bk], 32x32 tile/wave.
// Blocks 512..767: VsT[b][c][m] = (xsum[b] @ Wv^T + 16*bv)^T, 32x32 tile/wave.
// A frag: X[m=lane&15][k=quad*8+j]; B frag: W[n=lane&15][k=quad*8+j]
// D: col = lane&15 (N), row = quad*4+reg (M).            [guide §3, m89/m91]
// ---------------------------------------------------------------------------
__global__ void proj_gemm(const unsigned short* __restrict__ xavg,
                          const unsigned short* __restrict__ xsum,
                          const unsigned short* __restrict__ Wb,
                          const float* __restrict__ bq,
                          const float* __restrict__ bk,
                          const float* __restrict__ bv,
                          unsigned short* __restrict__ QK,
                          unsigned short* __restrict__ VsT)
{
    const int blk = blockIdx.x;
    const int lane = threadIdx.x & 63, quad = lane >> 4, r16 = lane & 15;
    const int w = threadIdx.x >> 6;

    if (blk < 512) {                        // ---- QK projection ----
        const int wave = blk * 4 + w;       // 0..2047
        const int mt2 = wave >> 5, nt2 = wave & 31;
        const unsigned short* xp0 = xavg + (size_t)(mt2 * 32 + r16) * 512 + quad * 8;
        const unsigned short* xp1 = xp0 + 16 * 512;
        const unsigned short* wp0 = Wb + (size_t)(nt2 * 32 + r16) * 512 + quad * 8;
        const unsigned short* wp1 = wp0 + 16 * 512;

        f32x4 acc00 = {0,0,0,0}, acc01 = acc00, acc10 = acc00, acc11 = acc00;
#pragma unroll 4
        for (int k = 0; k < 512; k += 32) {
            short8 a0 = *(const short8*)(xp0 + k);
            short8 a1 = *(const short8*)(xp1 + k);
            short8 b0 = *(const short8*)(wp0 + k);
            short8 b1 = *(const short8*)(wp1 + k);
            acc00 = mfma16(a0, b0, acc00);
            acc01 = mfma16(a0, b1, acc01);
            acc10 = mfma16(a1, b0, acc10);
            acc11 = mfma16(a1, b1, acc11);
        }
        const int c0 = nt2 * 32 + r16, c1 = c0 + 16;
        const float bias0 = (c0 < 512) ? bq[c0] : bk[c0 - 512];
        const float bias1 = (c1 < 512) ? bq[c1] : bk[c1 - 512];
        const int row0 = mt2 * 32 + quad * 4;
#pragma unroll
        for (int r = 0; r < 4; ++r) {
            QK[(size_t)(row0 + r) * 1024 + c0]      = f2bf(acc00[r] + bias0);
            QK[(size_t)(row0 + r) * 1024 + c1]      = f2bf(acc01[r] + bias1);
            QK[(size_t)(row0 + 16 + r) * 1024 + c0] = f2bf(acc10[r] + bias0);
            QK[(size_t)(row0 + 16 + r) * 1024 + c1] = f2bf(acc11[r] + bias1);
        }
    } else {                                // ---- V projection (transposed) ----
        const int vblk = blk - 512;         // 0..255
        const int b = vblk >> 5;
        const int wave = (vblk & 31) * 4 + w;   // 0..127
        const int mt2 = wave >> 4, nt2 = wave & 15;
        const unsigned short* xp0 = xsum + (size_t)b * 131072 + (size_t)(mt2 * 32 + r16) * 512 + quad * 8;
        const unsigned short* xp1 = xp0 + 16 * 512;
        const unsigned short* wp0 = Wb + 524288 + (size_t)(nt2 * 32 + r16) * 512 + quad * 8;
        const unsigned short* wp1 = wp0 + 16 * 512;

        f32x4 acc00 = {0,0,0,0}, acc01 = acc00, acc10 = acc00, acc11 = acc00;
#pragma unroll 4
        for (int k = 0; k < 512; k += 32) {
            short8 a0 = *(const short8*)(xp0 + k);
            short8 a1 = *(const short8*)(xp1 + k);
            short8 b0 = *(const short8*)(wp0 + k);
            short8 b1 = *(const short8*)(wp1 + k);
            acc00 = mfma16(a0, b0, acc00);
            acc01 = mfma16(a0, b1, acc01);
            acc10 = mfma16(a1, b0, acc10);
            acc11 = mfma16(a1, b1, acc11);
        }
        const int c0 = nt2 * 32 + r16, c1 = c0 + 16;
        const float bias0 = 16.f * bv[c0], bias1 = 16.f * bv[c1];
        unsigned short* vb = VsT + (size_t)b * 131072;
        const int m0 = mt2 * 32 + quad * 4;
#pragma unroll
        for (int r = 0; r < 4; ++r) {
            vb[(size_t)c0 * 256 + m0 + r]      = f2bf(acc00[r] + bias0);
            vb[(size_t)c1 * 256 + m0 + r]      = f2bf(acc01[r] + bias1);
            vb[(size_t)c0 * 256 + m0 + 16 + r] = f2bf(acc10[r] + bias0);
            vb[(size_t)c1 * 256 + m0 + 16 + r] = f2bf(acc11[r] + bias1);
        }
    }
}

// ---------------------------------------------------------------------------
// K3: fused scores + softmax + (A @ Vsum) + 16x pixel expansion.
// Block = (strip of 32 A-rows, c-eighth of 64 channels) x batch: 512 blocks,
// 2 blocks/CU (LDS ~49.5 KB), 8 waves/CU.
// Phase A: 4 waves compute the 32x256 fp32 score strip (K=512) into LDS S
//          (duplicated across the 8 c-eighth siblings - cheap MFMA).
// Phase B: softmax rows -> bf16 A in LDS Abf (row stride 264: b128 reads
//          alias banks only 2-way = free [m136]).
// Phase C: each wave computes out_small[32n x 16c] = A_strip @ Vsum (K=256,
//          A-frags from LDS, V-frags from global VsT), transposes through
//          LDS osT[ch][n] (stride 33, conflict-free), then all 256 threads
//          write d_out fully coalesced (contiguous 2 KB runs per channel).
// Reads only d_ws; d_out written exactly once.
// ---------------------------------------------------------------------------
__global__ void attn_out(const unsigned short* __restrict__ QK,
                         const unsigned short* __restrict__ VsT,
                         float* __restrict__ out)
{
    __shared__ float S[32][257];                 // 32.9 KB; dead after Phase B
    __shared__ unsigned short Abf[32 * 264];     // 16.5 KB
    float (*osT)[33] = (float(*)[33])&S[0][0];   // 64x33 fp32 = 8.4 KB, unioned

    const int b = blockIdx.y;
    const int strip = blockIdx.x >> 3;      // 0..7 (32 A-rows)
    const int cq = blockIdx.x & 7;          // 0..7 (64 channels)
    const int w = threadIdx.x >> 6, lane = threadIdx.x & 63;
    const int quad = lane >> 4, r16 = lane & 15;

    // ---- Phase A: scores (32 rows x 256 cols), K = 512 ----
    const unsigned short* qp0 = QK + (size_t)(b * 256 + strip * 32 + r16) * 1024 + quad * 8;
    const unsigned short* qp1 = qp0 + 16 * 1024;
#pragma unroll
    for (int g = 0; g < 2; ++g) {
        const int ct = w * 2 + g;           // col tile 0..7
        const unsigned short* kp0 = QK + (size_t)(b * 256 + ct * 32 + r16) * 1024 + 512 + quad * 8;
        const unsigned short* kp1 = kp0 + 16 * 1024;
        f32x4 acc00 = {0,0,0,0}, acc01 = acc00, acc10 = acc00, acc11 = acc00;
#pragma unroll 4
        for (int k = 0; k < 512; k += 32) {
            short8 a0 = *(const short8*)(qp0 + k);
            short8 a1 = *(const short8*)(qp1 + k);
            short8 b0 = *(const short8*)(kp0 + k);
            short8 b1 = *(const short8*)(kp1 + k);
            acc00 = mfma16(a0, b0, acc00);
            acc01 = mfma16(a0, b1, acc01);
            acc10 = mfma16(a1, b0, acc10);
            acc11 = mfma16(a1, b1, acc11);
        }
        const int col0 = ct * 32 + r16;
#pragma unroll
        for (int r = 0; r < 4; ++r) {
            S[quad * 4 + r][col0]           = acc00[r];
            S[quad * 4 + r][col0 + 16]      = acc01[r];
            S[quad * 4 + 16 + r][col0]      = acc10[r];
            S[quad * 4 + 16 + r][col0 + 16] = acc11[r];
        }
    }
    __syncthreads();

    // ---- Phase B: softmax rows -> bf16 A (LDS) ----
    {
        const int t = threadIdx.x;
        const int r = t >> 3, seg = t & 7;  // row r, cols seg*32..+32
        float v[32];
        float mx = -3.4e38f;
#pragma unroll
        for (int j = 0; j < 32; ++j) {
            v[j] = S[r][seg * 32 + j] * 0.044194173824159216f;
            mx = fmaxf(mx, v[j]);
        }
        mx = fmaxf(mx, __shfl_xor(mx, 1));
        mx = fmaxf(mx, __shfl_xor(mx, 2));
        mx = fmaxf(mx, __shfl_xor(mx, 4));
        float sum = 0.f;
#pragma unroll
        for (int j = 0; j < 32; ++j) { v[j] = __expf(v[j] - mx); sum += v[j]; }
        sum += __shfl_xor(sum, 1);
        sum += __shfl_xor(sum, 2);
        sum += __shfl_xor(sum, 4);
        const float inv = 1.f / sum;
        unsigned short* ap = Abf + r * 264 + seg * 32;
#pragma unroll
        for (int j = 0; j < 32; j += 4)
            *(ushort4*)(ap + j) = make_ushort4(f2bf(v[j] * inv), f2bf(v[j + 1] * inv),
                                               f2bf(v[j + 2] * inv), f2bf(v[j + 3] * inv));
    }
    __syncthreads();   // Abf ready; S dead from here (osT may overwrite)

    // ---- Phase C: out_small = A_strip @ Vsum, 32n x 16c per wave ----
    {
        const int ch = w * 16 + r16;        // wave's channel (0..63 local)
        const unsigned short* ap0 = Abf + r16 * 264 + quad * 8;
        const unsigned short* ap1 = ap0 + 16 * 264;
        const unsigned short* vp  = VsT + (size_t)b * 131072 +
                                    (size_t)(cq * 64 + ch) * 256 + quad * 8;
        f32x4 acc0 = {0,0,0,0}, acc1 = acc0;
#pragma unroll 4
        for (int k = 0; k < 256; k += 32) {
            short8 a0 = *(const short8*)(ap0 + k);
            short8 a1 = *(const short8*)(ap1 + k);
            short8 b0 = *(const short8*)(vp + k);
            acc0 = mfma16(a0, b0, acc0);
            acc1 = mfma16(a1, b0, acc1);
        }
        // acc0[r]: (n = quad*4+r, c = ch); acc1: n+16. Transpose via LDS.
#pragma unroll
        for (int r = 0; r < 4; ++r) {
            osT[ch][quad * 4 + r]      = acc0[r];
            osT[ch][quad * 4 + 16 + r] = acc1[r];
        }
    }
    __syncthreads();

    // ---- Phase D: coalesced expand-write. Per channel: 512 consecutive
    // pixels (2 KB) = 128 float4s written by 128 consecutive threads. ----
    {
        const int t = threadIdx.x;
        const int ch2 = t >> 7;             // 0/1: two channels per pass
        const int j = t & 127;              // float4 index within channel
        const int n = j >> 2;               // local block-row 0..31
        float* obase = out + (size_t)(b * 512 + cq * 64) * 4096 + strip * 512 + j * 4;
#pragma unroll
        for (int it = 0; it < 32; ++it) {
            const int ch = it * 2 + ch2;
            const float v = osT[ch][n];
            *(float4*)(obase + (size_t)ch * 4096) = make_float4(v, v, v, v);
        }
    }
}

extern "C" void kernel_launch(void* const* d_in, const int* in_sizes, int n_in,
                              void* d_out, int out_size, void* d_ws, size_t ws_size,
                              hipStream_t stream) {
    const float* x  = (const float*)d_in[0];
    const float* Wq = (const float*)d_in[1];
    const float* bq = (const float*)d_in[2];
    const float* Wk = (const float*)d_in[3];
    const float* bk = (const float*)d_in[4];
    const float* Wv = (const float*)d_in[5];
    const float* bv = (const float*)d_in[6];
    float* out = (float*)d_out;

    // All scratch in d_ws (11.5 MB); fully written before read each call.
    // d_out is written exactly once (by attn_out).
    unsigned short* Wb   = (unsigned short*)d_ws;    // 786432 shorts (Wq|Wk|Wv)
    unsigned short* xavg = Wb + 786432;              // 1048576
    unsigned short* xsum = xavg + 1048576;           // 1048576
    unsigned short* QK   = xsum + 1048576;           // 2097152 (2048x1024)
    unsigned short* VsT  = QK + 2097152;             // 1048576 (8 x 512x256)

    // K1: plane reductions (4096 blocks) + weight convert (384 blocks)
    prep_kernel<<<4480, 256, 0, stream>>>(x, Wq, Wk, Wv, xavg, xsum, Wb);
    // K2: QK = xavg @ [Wq;Wk]^T + bias  AND  VsT = (xsum @ Wv^T + 16*bv)^T
    proj_gemm<<<768, 256, 0, stream>>>(xavg, xsum, Wb, bq, bk, bv, QK, VsT);
    // K3: per (strip, c-eighth, batch): scores+softmax+AV+expand -> d_out
    attn_out<<<dim3(64, 8), 256, 0, stream>>>(QK, VsT, out);
}

// Round 9
// 187.582 us; speedup vs baseline: 1.1553x; 1.0288x over previous
//
#include <hip/hip_runtime.h>

typedef __attribute__((ext_vector_type(8))) short short8;
typedef __attribute__((ext_vector_type(4))) float f32x4;

__device__ __forceinline__ unsigned short f2bf(float f) {
    union { float f; unsigned int i; } v; v.f = f;
    unsigned int x = v.i;
    return (unsigned short)((x + 0x7FFFu + ((x >> 16) & 1u)) >> 16); // RNE, finite inputs
}
__device__ __forceinline__ f32x4 mfma16(short8 a, short8 b, f32x4 c) {
    return __builtin_amdgcn_mfma_f32_16x16x32_bf16(a, b, c, 0, 0, 0);
}

// ---------------------------------------------------------------------------
// K1: fused input prep (coalesced, HBM-bound; unchanged).
// Blocks 0..4095: per (b,c) plane of fp32 x -> xsum (16-pixel group sums) +
// xavg (4x4 block means), bf16. Blocks 4096..4479: Wq|Wk|Wv fp32->bf16 into
// contiguous Wb (Q rows 0..511, K rows 512..1023, V rows 1024..1535).
// ---------------------------------------------------------------------------
__global__ void prep_kernel(const float* __restrict__ x,
                            const float* __restrict__ Wq,
                            const float* __restrict__ Wk,
                            const float* __restrict__ Wv,
                            unsigned short* __restrict__ xavg,
                            unsigned short* __restrict__ xsum,
                            unsigned short* __restrict__ Wb)
{
    const int blk = blockIdx.x;
    const int t = threadIdx.x;
    if (blk >= 4096) {                      // weight conversion
        const int i = (blk - 4096) * 256 + t;
        const int m = i >> 15;              // 32768 threads per matrix
        const int o = (i & 32767) * 8;
        const float* src = (m == 0) ? Wq : (m == 1) ? Wk : Wv;
        unsigned short* dst = Wb + m * 262144 + o;
        float4 a = *(const float4*)(src + o);
        float4 b = *(const float4*)(src + o + 4);
        *(ushort4*)(dst)     = make_ushort4(f2bf(a.x), f2bf(a.y), f2bf(a.z), f2bf(a.w));
        *(ushort4*)(dst + 4) = make_ushort4(f2bf(b.x), f2bf(b.y), f2bf(b.z), f2bf(b.w));
        return;
    }
    const int b = blk >> 9;                 // plane = b*512 + c
    const int c = blk & 511;

    const float4* p = (const float4*)(x + (size_t)blk * 4096) + t * 4;
    float4 a0 = p[0], a1 = p[1], a2 = p[2], a3 = p[3];
    float s0 = a0.x + a0.y + a0.z + a0.w;
    float s1 = a1.x + a1.y + a1.z + a1.w;
    float s2 = a2.x + a2.y + a2.z + a2.w;
    float s3 = a3.x + a3.y + a3.z + a3.w;

    xsum[((size_t)b * 256 + t) * 512 + c] = f2bf(s0 + s1 + s2 + s3);

    __shared__ float part[1024];
    ((float4*)part)[t] = make_float4(s0, s1, s2, s3);
    __syncthreads();

    const int bh = t >> 4, bw = t & 15;     // spatial block n = t
    float m = (part[(bh * 4 + 0) * 16 + bw] + part[(bh * 4 + 1) * 16 + bw] +
               part[(bh * 4 + 2) * 16 + bw] + part[(bh * 4 + 3) * 16 + bw]) * 0.0625f;
    xavg[((size_t)b * 256 + t) * 512 + c] = f2bf(m);
}

// ---------------------------------------------------------------------------
// K2: joint projection kernel (384 blocks). 32x64 tile per wave: A-fragments
// loaded ONCE for 4 N-tiles, 6 loads -> 8 MFMAs per K-step, 8 indep chains.
// __launch_bounds__(256,2): 256-VGPR budget so the unrolled loop keeps loads
// in flight (round-8 post-mortem: 28 VGPRs serialized every load).
// Blocks 0..255:  QK[2048x1024] = xavg @ [Wq;Wk]^T + [bq;bk].
// Blocks 256..383: VsT[b][c][m] = (xsum[b] @ Wv^T + 16*bv)^T.
// ---------------------------------------------------------------------------
__global__ void __launch_bounds__(256, 2)
proj_gemm(const unsigned short* __restrict__ xavg,
          const unsigned short* __restrict__ xsum,
          const unsigned short* __restrict__ Wb,
          const float* __restrict__ bq,
          const float* __restrict__ bk,
          const float* __restrict__ bv,
          unsigned short* __restrict__ QK,
          unsigned short* __restrict__ VsT)
{
    const int blk = blockIdx.x;
    const int lane = threadIdx.x & 63, quad = lane >> 4, r16 = lane & 15;
    const int w = threadIdx.x >> 6;

    if (blk < 256) {                        // ---- QK projection ----
        const int wave = blk * 4 + w;       // 0..1023
        const int mt2 = wave >> 4;          // 0..63 (32-row tiles)
        const int nt4 = wave & 15;          // 0..15 (64-col tiles)
        const unsigned short* xp0 = xavg + (size_t)(mt2 * 32 + r16) * 512 + quad * 8;
        const unsigned short* xp1 = xp0 + 16 * 512;
        const unsigned short* wp0 = Wb + (size_t)(nt4 * 64 + r16) * 512 + quad * 8;
        const unsigned short* wp1 = wp0 + 16 * 512;
        const unsigned short* wp2 = wp0 + 32 * 512;
        const unsigned short* wp3 = wp0 + 48 * 512;

        f32x4 a00 = {0,0,0,0}, a01 = a00, a02 = a00, a03 = a00;
        f32x4 a10 = a00, a11 = a00, a12 = a00, a13 = a00;
#pragma unroll 4
        for (int k = 0; k < 512; k += 32) {
            short8 qa0 = *(const short8*)(xp0 + k);
            short8 qa1 = *(const short8*)(xp1 + k);
            short8 b0 = *(const short8*)(wp0 + k);
            short8 b1 = *(const short8*)(wp1 + k);
            short8 b2 = *(const short8*)(wp2 + k);
            short8 b3 = *(const short8*)(wp3 + k);
            a00 = mfma16(qa0, b0, a00); a01 = mfma16(qa0, b1, a01);
            a02 = mfma16(qa0, b2, a02); a03 = mfma16(qa0, b3, a03);
            a10 = mfma16(qa1, b0, a10); a11 = mfma16(qa1, b1, a11);
            a12 = mfma16(qa1, b2, a12); a13 = mfma16(qa1, b3, a13);
        }
        const int row0 = mt2 * 32 + quad * 4;
        f32x4 accs0[4] = {a00, a01, a02, a03};
        f32x4 accs1[4] = {a10, a11, a12, a13};
#pragma unroll
        for (int j = 0; j < 4; ++j) {
            const int c = nt4 * 64 + j * 16 + r16;
            const float bias = (c < 512) ? bq[c] : bk[c - 512];
#pragma unroll
            for (int r = 0; r < 4; ++r) {
                QK[(size_t)(row0 + r) * 1024 + c]      = f2bf(accs0[j][r] + bias);
                QK[(size_t)(row0 + 16 + r) * 1024 + c] = f2bf(accs1[j][r] + bias);
            }
        }
    } else {                                // ---- V projection (transposed) ----
        const int vblk = blk - 256;         // 0..127
        const int b = vblk >> 4;            // 0..7
        const int wave = (vblk & 15) * 4 + w;   // 0..63
        const int mt2 = wave >> 3;          // 0..7
        const int nt4 = wave & 7;           // 0..7
        const unsigned short* xp0 = xsum + (size_t)b * 131072 + (size_t)(mt2 * 32 + r16) * 512 + quad * 8;
        const unsigned short* xp1 = xp0 + 16 * 512;
        const unsigned short* wp0 = Wb + 524288 + (size_t)(nt4 * 64 + r16) * 512 + quad * 8;
        const unsigned short* wp1 = wp0 + 16 * 512;
        const unsigned short* wp2 = wp0 + 32 * 512;
        const unsigned short* wp3 = wp0 + 48 * 512;

        f32x4 a00 = {0,0,0,0}, a01 = a00, a02 = a00, a03 = a00;
        f32x4 a10 = a00, a11 = a00, a12 = a00, a13 = a00;
#pragma unroll 4
        for (int k = 0; k < 512; k += 32) {
            short8 qa0 = *(const short8*)(xp0 + k);
            short8 qa1 = *(const short8*)(xp1 + k);
            short8 b0 = *(const short8*)(wp0 + k);
            short8 b1 = *(const short8*)(wp1 + k);
            short8 b2 = *(const short8*)(wp2 + k);
            short8 b3 = *(const short8*)(wp3 + k);
            a00 = mfma16(qa0, b0, a00); a01 = mfma16(qa0, b1, a01);
            a02 = mfma16(qa0, b2, a02); a03 = mfma16(qa0, b3, a03);
            a10 = mfma16(qa1, b0, a10); a11 = mfma16(qa1, b1, a11);
            a12 = mfma16(qa1, b2, a12); a13 = mfma16(qa1, b3, a13);
        }
        unsigned short* vb = VsT + (size_t)b * 131072;
        const int m0 = mt2 * 32 + quad * 4;
        f32x4 accs0[4] = {a00, a01, a02, a03};
        f32x4 accs1[4] = {a10, a11, a12, a13};
#pragma unroll
        for (int j = 0; j < 4; ++j) {
            const int c = nt4 * 64 + j * 16 + r16;
            const float bias = 16.f * bv[c];
#pragma unroll
            for (int r = 0; r < 4; ++r) {
                vb[(size_t)c * 256 + m0 + r]      = f2bf(accs0[j][r] + bias);
                vb[(size_t)c * 256 + m0 + 16 + r] = f2bf(accs1[j][r] + bias);
            }
        }
    }
}

// ---------------------------------------------------------------------------
// K3: fused scores + softmax + (A @ Vsum) + 16x pixel expansion.
// Block = (strip of 32 A-rows, c-eighth of 64 channels) x batch: 512 blocks.
// Phase A: each wave computes the strip vs a 64-col K-slab in ONE fused
//          K-loop (Q frags shared: 6 loads -> 8 MFMAs, 8 indep chains).
// Phase B: softmax rows -> bf16 A in LDS.
// Phase C: out_small = A_strip @ Vsum (A from LDS, V from global).
// Phase D: transpose via LDS, fully-coalesced expand-write of d_out.
// __launch_bounds__(256,2) for the VGPR budget (see round-8 post-mortem).
// ---------------------------------------------------------------------------
__global__ void __launch_bounds__(256, 2)
attn_out(const unsigned short* __restrict__ QK,
         const unsigned short* __restrict__ VsT,
         float* __restrict__ out)
{
    __shared__ float S[32][257];                 // 32.9 KB; dead after Phase B
    __shared__ unsigned short Abf[32 * 264];     // 16.5 KB
    float (*osT)[33] = (float(*)[33])&S[0][0];   // 64x33 fp32, unioned with S

    const int b = blockIdx.y;
    const int strip = blockIdx.x >> 3;      // 0..7 (32 A-rows)
    const int cq = blockIdx.x & 7;          // 0..7 (64 channels)
    const int w = threadIdx.x >> 6, lane = threadIdx.x & 63;
    const int quad = lane >> 4, r16 = lane & 15;

    // ---- Phase A: scores (32 rows x 64 cols per wave), K = 512 ----
    {
        const unsigned short* qp0 = QK + (size_t)(b * 256 + strip * 32 + r16) * 1024 + quad * 8;
        const unsigned short* qp1 = qp0 + 16 * 1024;
        const unsigned short* kp0 = QK + (size_t)(b * 256 + w * 64 + r16) * 1024 + 512 + quad * 8;
        const unsigned short* kp1 = kp0 + 16 * 1024;
        const unsigned short* kp2 = kp0 + 32 * 1024;
        const unsigned short* kp3 = kp0 + 48 * 1024;

        f32x4 a00 = {0,0,0,0}, a01 = a00, a02 = a00, a03 = a00;
        f32x4 a10 = a00, a11 = a00, a12 = a00, a13 = a00;
#pragma unroll 4
        for (int k = 0; k < 512; k += 32) {
            short8 qa0 = *(const short8*)(qp0 + k);
            short8 qa1 = *(const short8*)(qp1 + k);
            short8 b0 = *(const short8*)(kp0 + k);
            short8 b1 = *(const short8*)(kp1 + k);
            short8 b2 = *(const short8*)(kp2 + k);
            short8 b3 = *(const short8*)(kp3 + k);
            a00 = mfma16(qa0, b0, a00); a01 = mfma16(qa0, b1, a01);
            a02 = mfma16(qa0, b2, a02); a03 = mfma16(qa0, b3, a03);
            a10 = mfma16(qa1, b0, a10); a11 = mfma16(qa1, b1, a11);
            a12 = mfma16(qa1, b2, a12); a13 = mfma16(qa1, b3, a13);
        }
        f32x4 accs0[4] = {a00, a01, a02, a03};
        f32x4 accs1[4] = {a10, a11, a12, a13};
#pragma unroll
        for (int j = 0; j < 4; ++j) {
            const int col = w * 64 + j * 16 + r16;
#pragma unroll
            for (int r = 0; r < 4; ++r) {
                S[quad * 4 + r][col]      = accs0[j][r];
                S[quad * 4 + 16 + r][col] = accs1[j][r];
            }
        }
    }
    __syncthreads();

    // ---- Phase B: softmax rows -> bf16 A (LDS) ----
    {
        const int t = threadIdx.x;
        const int r = t >> 3, seg = t & 7;  // row r, cols seg*32..+32
        float v[32];
        float mx = -3.4e38f;
#pragma unroll
        for (int j = 0; j < 32; ++j) {
            v[j] = S[r][seg * 32 + j] * 0.044194173824159216f;
            mx = fmaxf(mx, v[j]);
        }
        mx = fmaxf(mx, __shfl_xor(mx, 1));
        mx = fmaxf(mx, __shfl_xor(mx, 2));
        mx = fmaxf(mx, __shfl_xor(mx, 4));
        float sum = 0.f;
#pragma unroll
        for (int j = 0; j < 32; ++j) { v[j] = __expf(v[j] - mx); sum += v[j]; }
        sum += __shfl_xor(sum, 1);
        sum += __shfl_xor(sum, 2);
        sum += __shfl_xor(sum, 4);
        const float inv = 1.f / sum;
        unsigned short* ap = Abf + r * 264 + seg * 32;
#pragma unroll
        for (int j = 0; j < 32; j += 4)
            *(ushort4*)(ap + j) = make_ushort4(f2bf(v[j] * inv), f2bf(v[j + 1] * inv),
                                               f2bf(v[j + 2] * inv), f2bf(v[j + 3] * inv));
    }
    __syncthreads();   // Abf ready; S dead from here (osT may overwrite)

    // ---- Phase C: out_small = A_strip @ Vsum, 32n x 16c per wave ----
    {
        const int ch = w * 16 + r16;        // wave's channel (0..63 local)
        const unsigned short* ap0 = Abf + r16 * 264 + quad * 8;
        const unsigned short* ap1 = ap0 + 16 * 264;
        const unsigned short* vp  = VsT + (size_t)b * 131072 +
                                    (size_t)(cq * 64 + ch) * 256 + quad * 8;
        f32x4 acc0 = {0,0,0,0}, acc1 = acc0;
#pragma unroll
        for (int k = 0; k < 256; k += 32) {
            short8 a0 = *(const short8*)(ap0 + k);
            short8 a1 = *(const short8*)(ap1 + k);
            short8 b0 = *(const short8*)(vp + k);
            acc0 = mfma16(a0, b0, acc0);
            acc1 = mfma16(a1, b0, acc1);
        }
        // acc0[r]: (n = quad*4+r, c = ch); acc1: n+16. Transpose via LDS.
#pragma unroll
        for (int r = 0; r < 4; ++r) {
            osT[ch][quad * 4 + r]      = acc0[r];
            osT[ch][quad * 4 + 16 + r] = acc1[r];
        }
    }
    __syncthreads();

    // ---- Phase D: coalesced expand-write. Per channel: 512 consecutive
    // pixels (2 KB) = 128 float4s written by 128 consecutive threads. ----
    {
        const int t = threadIdx.x;
        const int ch2 = t >> 7;             // 0/1: two channels per pass
        const int j = t & 127;              // float4 index within channel
        const int n = j >> 2;               // local block-row 0..31
        float* obase = out + (size_t)(b * 512 + cq * 64) * 4096 + strip * 512 + j * 4;
#pragma unroll
        for (int it = 0; it < 32; ++it) {
            const int ch = it * 2 + ch2;
            const float v = osT[ch][n];
            *(float4*)(obase + (size_t)ch * 4096) = make_float4(v, v, v, v);
        }
    }
}

extern "C" void kernel_launch(void* const* d_in, const int* in_sizes, int n_in,
                              void* d_out, int out_size, void* d_ws, size_t ws_size,
                              hipStream_t stream) {
    const float* x  = (const float*)d_in[0];
    const float* Wq = (const float*)d_in[1];
    const float* bq = (const float*)d_in[2];
    const float* Wk = (const float*)d_in[3];
    const float* bk = (const float*)d_in[4];
    const float* Wv = (const float*)d_in[5];
    const float* bv = (const float*)d_in[6];
    float* out = (float*)d_out;

    // All scratch in d_ws (11.5 MB); fully written before read each call.
    // d_out is written exactly once (by attn_out).
    unsigned short* Wb   = (unsigned short*)d_ws;    // 786432 shorts (Wq|Wk|Wv)
    unsigned short* xavg = Wb + 786432;              // 1048576
    unsigned short* xsum = xavg + 1048576;           // 1048576
    unsigned short* QK   = xsum + 1048576;           // 2097152 (2048x1024)
    unsigned short* VsT  = QK + 2097152;             // 1048576 (8 x 512x256)

    // K1: plane reductions (4096 blocks) + weight convert (384 blocks)
    prep_kernel<<<4480, 256, 0, stream>>>(x, Wq, Wk, Wv, xavg, xsum, Wb);
    // K2: QK = xavg @ [Wq;Wk]^T + bias  AND  VsT = (xsum @ Wv^T + 16*bv)^T
    proj_gemm<<<384, 256, 0, stream>>>(xavg, xsum, Wb, bq, bk, bv, QK, VsT);
    // K3: per (strip, c-eighth, batch): scores+softmax+AV+expand -> d_out
    attn_out<<<dim3(64, 8), 256, 0, stream>>>(QK, VsT, out);
}

// Round 10
// 182.072 us; speedup vs baseline: 1.1903x; 1.0303x over previous
//
#include <hip/hip_runtime.h>

typedef __attribute__((ext_vector_type(8))) short short8;
typedef __attribute__((ext_vector_type(4))) float f32x4;

__device__ __forceinline__ unsigned short f2bf(float f) {
    union { float f; unsigned int i; } v; v.f = f;
    unsigned int x = v.i;
    return (unsigned short)((x + 0x7FFFu + ((x >> 16) & 1u)) >> 16); // RNE, finite inputs
}
__device__ __forceinline__ f32x4 mfma16(short8 a, short8 b, f32x4 c) {
    return __builtin_amdgcn_mfma_f32_16x16x32_bf16(a, b, c, 0, 0, 0);
}

// ---------------------------------------------------------------------------
// K1: fused input prep (coalesced, HBM-bound).
// Blocks 0..4095: per (b,c) plane of fp32 x -> xsum (16-pixel group sums) +
// xavg (4x4 block means), bf16. Blocks 4096..4479: Wq|Wk|Wv fp32->bf16 into
// contiguous Wb.
// ---------------------------------------------------------------------------
__global__ void prep_kernel(const float* __restrict__ x,
                            const float* __restrict__ Wq,
                            const float* __restrict__ Wk,
                            const float* __restrict__ Wv,
                            unsigned short* __restrict__ xavg,
                            unsigned short* __restrict__ xsum,
                            unsigned short* __restrict__ Wb)
{
    const int blk = blockIdx.x;
    const int t = threadIdx.x;
    if (blk >= 4096) {                      // weight conversion
        const int i = (blk - 4096) * 256 + t;
        const int m = i >> 15;              // 32768 threads per matrix
        const int o = (i & 32767) * 8;
        const float* src = (m == 0) ? Wq : (m == 1) ? Wk : Wv;
        unsigned short* dst = Wb + m * 262144 + o;
        float4 a = *(const float4*)(src + o);
        float4 b = *(const float4*)(src + o + 4);
        *(ushort4*)(dst)     = make_ushort4(f2bf(a.x), f2bf(a.y), f2bf(a.z), f2bf(a.w));
        *(ushort4*)(dst + 4) = make_ushort4(f2bf(b.x), f2bf(b.y), f2bf(b.z), f2bf(b.w));
        return;
    }
    const int b = blk >> 9;                 // plane = b*512 + c
    const int c = blk & 511;

    const float4* p = (const float4*)(x + (size_t)blk * 4096) + t * 4;
    float4 a0 = p[0], a1 = p[1], a2 = p[2], a3 = p[3];
    float s0 = a0.x + a0.y + a0.z + a0.w;
    float s1 = a1.x + a1.y + a1.z + a1.w;
    float s2 = a2.x + a2.y + a2.z + a2.w;
    float s3 = a3.x + a3.y + a3.z + a3.w;

    xsum[((size_t)b * 256 + t) * 512 + c] = f2bf(s0 + s1 + s2 + s3);

    __shared__ float part[1024];
    ((float4*)part)[t] = make_float4(s0, s1, s2, s3);
    __syncthreads();

    const int bh = t >> 4, bw = t & 15;     // spatial block n = t
    float m = (part[(bh * 4 + 0) * 16 + bw] + part[(bh * 4 + 1) * 16 + bw] +
               part[(bh * 4 + 2) * 16 + bw] + part[(bh * 4 + 3) * 16 + bw]) * 0.0625f;
    xavg[((size_t)b * 256 + t) * 512 + c] = f2bf(m);
}

// ---------------------------------------------------------------------------
// K2: joint projection (384 blocks). 32x64 tile/wave, 6 loads -> 8 MFMAs.
// Blocks 0..255:  QK[2048x1024] = xavg @ [Wq;Wk]^T + [bq;bk].
// Blocks 256..383: VsT[b][c][m] = (xsum[b] @ Wv^T + 16*bv)^T.
// ---------------------------------------------------------------------------
__global__ void __launch_bounds__(256, 2)
proj_gemm(const unsigned short* __restrict__ xavg,
          const unsigned short* __restrict__ xsum,
          const unsigned short* __restrict__ Wb,
          const float* __restrict__ bq,
          const float* __restrict__ bk,
          const float* __restrict__ bv,
          unsigned short* __restrict__ QK,
          unsigned short* __restrict__ VsT)
{
    const int blk = blockIdx.x;
    const int lane = threadIdx.x & 63, quad = lane >> 4, r16 = lane & 15;
    const int w = threadIdx.x >> 6;

    if (blk < 256) {                        // ---- QK projection ----
        const int wave = blk * 4 + w;       // 0..1023
        const int mt2 = wave >> 4;          // 0..63 (32-row tiles)
        const int nt4 = wave & 15;          // 0..15 (64-col tiles)
        const unsigned short* xp0 = xavg + (size_t)(mt2 * 32 + r16) * 512 + quad * 8;
        const unsigned short* xp1 = xp0 + 16 * 512;
        const unsigned short* wp0 = Wb + (size_t)(nt4 * 64 + r16) * 512 + quad * 8;
        const unsigned short* wp1 = wp0 + 16 * 512;
        const unsigned short* wp2 = wp0 + 32 * 512;
        const unsigned short* wp3 = wp0 + 48 * 512;

        f32x4 a00 = {0,0,0,0}, a01 = a00, a02 = a00, a03 = a00;
        f32x4 a10 = a00, a11 = a00, a12 = a00, a13 = a00;
#pragma unroll 4
        for (int k = 0; k < 512; k += 32) {
            short8 qa0 = *(const short8*)(xp0 + k);
            short8 qa1 = *(const short8*)(xp1 + k);
            short8 b0 = *(const short8*)(wp0 + k);
            short8 b1 = *(const short8*)(wp1 + k);
            short8 b2 = *(const short8*)(wp2 + k);
            short8 b3 = *(const short8*)(wp3 + k);
            a00 = mfma16(qa0, b0, a00); a01 = mfma16(qa0, b1, a01);
            a02 = mfma16(qa0, b2, a02); a03 = mfma16(qa0, b3, a03);
            a10 = mfma16(qa1, b0, a10); a11 = mfma16(qa1, b1, a11);
            a12 = mfma16(qa1, b2, a12); a13 = mfma16(qa1, b3, a13);
        }
        const int row0 = mt2 * 32 + quad * 4;
        f32x4 accs0[4] = {a00, a01, a02, a03};
        f32x4 accs1[4] = {a10, a11, a12, a13};
#pragma unroll
        for (int j = 0; j < 4; ++j) {
            const int c = nt4 * 64 + j * 16 + r16;
            const float bias = (c < 512) ? bq[c] : bk[c - 512];
#pragma unroll
            for (int r = 0; r < 4; ++r) {
                QK[(size_t)(row0 + r) * 1024 + c]      = f2bf(accs0[j][r] + bias);
                QK[(size_t)(row0 + 16 + r) * 1024 + c] = f2bf(accs1[j][r] + bias);
            }
        }
    } else {                                // ---- V projection (transposed) ----
        const int vblk = blk - 256;         // 0..127
        const int b = vblk >> 4;            // 0..7
        const int wave = (vblk & 15) * 4 + w;   // 0..63
        const int mt2 = wave >> 3;          // 0..7
        const int nt4 = wave & 7;           // 0..7
        const unsigned short* xp0 = xsum + (size_t)b * 131072 + (size_t)(mt2 * 32 + r16) * 512 + quad * 8;
        const unsigned short* xp1 = xp0 + 16 * 512;
        const unsigned short* wp0 = Wb + 524288 + (size_t)(nt4 * 64 + r16) * 512 + quad * 8;
        const unsigned short* wp1 = wp0 + 16 * 512;
        const unsigned short* wp2 = wp0 + 32 * 512;
        const unsigned short* wp3 = wp0 + 48 * 512;

        f32x4 a00 = {0,0,0,0}, a01 = a00, a02 = a00, a03 = a00;
        f32x4 a10 = a00, a11 = a00, a12 = a00, a13 = a00;
#pragma unroll 4
        for (int k = 0; k < 512; k += 32) {
            short8 qa0 = *(const short8*)(xp0 + k);
            short8 qa1 = *(const short8*)(xp1 + k);
            short8 b0 = *(const short8*)(wp0 + k);
            short8 b1 = *(const short8*)(wp1 + k);
            short8 b2 = *(const short8*)(wp2 + k);
            short8 b3 = *(const short8*)(wp3 + k);
            a00 = mfma16(qa0, b0, a00); a01 = mfma16(qa0, b1, a01);
            a02 = mfma16(qa0, b2, a02); a03 = mfma16(qa0, b3, a03);
            a10 = mfma16(qa1, b0, a10); a11 = mfma16(qa1, b1, a11);
            a12 = mfma16(qa1, b2, a12); a13 = mfma16(qa1, b3, a13);
        }
        unsigned short* vb = VsT + (size_t)b * 131072;
        const int m0 = mt2 * 32 + quad * 4;
        f32x4 accs0[4] = {a00, a01, a02, a03};
        f32x4 accs1[4] = {a10, a11, a12, a13};
#pragma unroll
        for (int j = 0; j < 4; ++j) {
            const int c = nt4 * 64 + j * 16 + r16;
            const float bias = 16.f * bv[c];
#pragma unroll
            for (int r = 0; r < 4; ++r) {
                vb[(size_t)c * 256 + m0 + r]      = f2bf(accs0[j][r] + bias);
                vb[(size_t)c * 256 + m0 + 16 + r] = f2bf(accs1[j][r] + bias);
            }
        }
    }
}

// ---------------------------------------------------------------------------
// K3: scores + softmax, computed ONCE per strip (was 8x duplicated).
// Grid (8 strips, 8 batches) = 64 blocks. 4 waves: each computes the 32-row
// strip vs a 64-col K-slab (6 loads -> 8 MFMAs, K=512) into LDS S; then
// softmax rows -> bf16 Amat in d_ws (coalesced 512 B rows).
// ---------------------------------------------------------------------------
__global__ void __launch_bounds__(256, 2)
score_softmax(const unsigned short* __restrict__ QK,
              unsigned short* __restrict__ Amat)
{
    __shared__ float S[32][257];
    const int b = blockIdx.y, strip = blockIdx.x;
    const int w = threadIdx.x >> 6, lane = threadIdx.x & 63;
    const int quad = lane >> 4, r16 = lane & 15;

    {
        const unsigned short* qp0 = QK + (size_t)(b * 256 + strip * 32 + r16) * 1024 + quad * 8;
        const unsigned short* qp1 = qp0 + 16 * 1024;
        const unsigned short* kp0 = QK + (size_t)(b * 256 + w * 64 + r16) * 1024 + 512 + quad * 8;
        const unsigned short* kp1 = kp0 + 16 * 1024;
        const unsigned short* kp2 = kp0 + 32 * 1024;
        const unsigned short* kp3 = kp0 + 48 * 1024;

        f32x4 a00 = {0,0,0,0}, a01 = a00, a02 = a00, a03 = a00;
        f32x4 a10 = a00, a11 = a00, a12 = a00, a13 = a00;
#pragma unroll 4
        for (int k = 0; k < 512; k += 32) {
            short8 qa0 = *(const short8*)(qp0 + k);
            short8 qa1 = *(const short8*)(qp1 + k);
            short8 b0 = *(const short8*)(kp0 + k);
            short8 b1 = *(const short8*)(kp1 + k);
            short8 b2 = *(const short8*)(kp2 + k);
            short8 b3 = *(const short8*)(kp3 + k);
            a00 = mfma16(qa0, b0, a00); a01 = mfma16(qa0, b1, a01);
            a02 = mfma16(qa0, b2, a02); a03 = mfma16(qa0, b3, a03);
            a10 = mfma16(qa1, b0, a10); a11 = mfma16(qa1, b1, a11);
            a12 = mfma16(qa1, b2, a12); a13 = mfma16(qa1, b3, a13);
        }
        f32x4 accs0[4] = {a00, a01, a02, a03};
        f32x4 accs1[4] = {a10, a11, a12, a13};
#pragma unroll
        for (int j = 0; j < 4; ++j) {
            const int col = w * 64 + j * 16 + r16;
#pragma unroll
            for (int r = 0; r < 4; ++r) {
                S[quad * 4 + r][col]      = accs0[j][r];
                S[quad * 4 + 16 + r][col] = accs1[j][r];
            }
        }
    }
    __syncthreads();

    {
        const int t = threadIdx.x;
        const int r = t >> 3, seg = t & 7;  // row r, cols seg*32..+32
        float v[32];
        float mx = -3.4e38f;
#pragma unroll
        for (int j = 0; j < 32; ++j) {
            v[j] = S[r][seg * 32 + j] * 0.044194173824159216f;
            mx = fmaxf(mx, v[j]);
        }
        mx = fmaxf(mx, __shfl_xor(mx, 1));
        mx = fmaxf(mx, __shfl_xor(mx, 2));
        mx = fmaxf(mx, __shfl_xor(mx, 4));
        float sum = 0.f;
#pragma unroll
        for (int j = 0; j < 32; ++j) { v[j] = __expf(v[j] - mx); sum += v[j]; }
        sum += __shfl_xor(sum, 1);
        sum += __shfl_xor(sum, 2);
        sum += __shfl_xor(sum, 4);
        const float inv = 1.f / sum;
        unsigned short* ap = Amat + (size_t)b * 65536 + (size_t)(strip * 32 + r) * 256 + seg * 32;
#pragma unroll
        for (int j = 0; j < 32; j += 4)
            *(ushort4*)(ap + j) = make_ushort4(f2bf(v[j] * inv), f2bf(v[j + 1] * inv),
                                               f2bf(v[j + 2] * inv), f2bf(v[j + 3] * inv));
    }
}

// ---------------------------------------------------------------------------
// K4: out = expand16(A @ Vsum). Grid (16 half-strips x 8 c-eighths, 8 b) =
// 1024 blocks, 4 blocks/CU (LDS 4.4 KB), 16 waves/CU. One 16x16 tile/wave
// (16 spatial blocks x 16 channels, K=256 fully unrolled, frags direct from
// global). Transpose via tiny LDS, then fully-coalesced 64 MiB write.
// Reads only d_ws; d_out written exactly once.
// ---------------------------------------------------------------------------
__global__ void __launch_bounds__(256, 4)
av_expand(const unsigned short* __restrict__ Amat,
          const unsigned short* __restrict__ VsT,
          float* __restrict__ out)
{
    __shared__ float osT[64][17];           // [local ch][local n]
    const int b = blockIdx.y;
    const int sh = blockIdx.x >> 3;         // 0..15: 16-row half-strip
    const int cq = blockIdx.x & 7;          // 0..7: 64-channel group
    const int w = threadIdx.x >> 6, lane = threadIdx.x & 63;
    const int quad = lane >> 4, r16 = lane & 15;

    {
        const unsigned short* ap = Amat + (size_t)b * 65536 + (size_t)(sh * 16 + r16) * 256 + quad * 8;
        const unsigned short* vp = VsT + (size_t)b * 131072 +
                                   (size_t)(cq * 64 + w * 16 + r16) * 256 + quad * 8;
        f32x4 acc = {0.f, 0.f, 0.f, 0.f};
#pragma unroll
        for (int k = 0; k < 256; k += 32) {
            short8 a0 = *(const short8*)(ap + k);
            short8 b0 = *(const short8*)(vp + k);
            acc = mfma16(a0, b0, acc);
        }
        // acc[r]: n_local = quad*4+r (A row), ch_local = w*16 + r16 (V row)
#pragma unroll
        for (int r = 0; r < 4; ++r)
            osT[w * 16 + r16][quad * 4 + r] = acc[r];
    }
    __syncthreads();

    // Coalesced expand-write: per channel 256 consecutive pixels (1 KB) by
    // 64 consecutive threads; each wave owns one channel per iteration.
    {
        const int t = threadIdx.x;
        const int ch4 = t >> 6;             // wave index: ch = it*4 + ch4
        const int j = t & 63;               // float4 index within channel
        const int n = j >> 2;               // local block-row 0..15
        float* obase = out + (size_t)(b * 512 + cq * 64) * 4096 + sh * 256 + j * 4;
#pragma unroll
        for (int it = 0; it < 16; ++it) {
            const int ch = it * 4 + ch4;
            const float v = osT[ch][n];
            *(float4*)(obase + (size_t)ch * 4096) = make_float4(v, v, v, v);
        }
    }
}

extern "C" void kernel_launch(void* const* d_in, const int* in_sizes, int n_in,
                              void* d_out, int out_size, void* d_ws, size_t ws_size,
                              hipStream_t stream) {
    const float* x  = (const float*)d_in[0];
    const float* Wq = (const float*)d_in[1];
    const float* bq = (const float*)d_in[2];
    const float* Wk = (const float*)d_in[3];
    const float* bk = (const float*)d_in[4];
    const float* Wv = (const float*)d_in[5];
    const float* bv = (const float*)d_in[6];
    float* out = (float*)d_out;

    // All scratch in d_ws (13 MB); fully written before read each call.
    // d_out written exactly once (by av_expand).
    unsigned short* Wb   = (unsigned short*)d_ws;    // 786432 shorts (Wq|Wk|Wv)
    unsigned short* xavg = Wb + 786432;              // 1048576
    unsigned short* xsum = xavg + 1048576;           // 1048576
    unsigned short* QK   = xsum + 1048576;           // 2097152 (2048x1024)
    unsigned short* VsT  = QK + 2097152;             // 1048576 (8 x 512x256)
    unsigned short* Amat = VsT + 1048576;            // 524288  (8 x 256x256)

    // K1: plane reductions (4096 blocks) + weight convert (384 blocks)
    prep_kernel<<<4480, 256, 0, stream>>>(x, Wq, Wk, Wv, xavg, xsum, Wb);
    // K2: QK = xavg @ [Wq;Wk]^T + bias  AND  VsT = (xsum @ Wv^T + 16*bv)^T
    proj_gemm<<<384, 256, 0, stream>>>(xavg, xsum, Wb, bq, bk, bv, QK, VsT);
    // K3: A = softmax(QK^T/sqrt(512)) once per strip -> Amat (d_ws)
    score_softmax<<<dim3(8, 8), 256, 0, stream>>>(QK, Amat);
    // K4: out = expand16(A @ Vsum), write-bound, high occupancy
    av_expand<<<dim3(128, 8), 256, 0, stream>>>(Amat, VsT, out);
}

// Round 11
// 180.598 us; speedup vs baseline: 1.2000x; 1.0082x over previous
//
#include <hip/hip_runtime.h>

typedef __attribute__((ext_vector_type(8))) short short8;
typedef __attribute__((ext_vector_type(4))) float f32x4;

__device__ __forceinline__ unsigned short f2bf(float f) {
    union { float f; unsigned int i; } v; v.f = f;
    unsigned int x = v.i;
    return (unsigned short)((x + 0x7FFFu + ((x >> 16) & 1u)) >> 16); // RNE, finite inputs
}
__device__ __forceinline__ f32x4 mfma16(short8 a, short8 b, f32x4 c) {
    return __builtin_amdgcn_mfma_f32_16x16x32_bf16(a, b, c, 0, 0, 0);
}

// ---------------------------------------------------------------------------
// K1: fused input prep, fully-coalesced loads (1 KB contiguous per wave instr).
// Blocks 0..4095: per (b,c) plane of fp32 x. Thread t loads float4s at
// {t, t+256, t+512, t+768}; partial quad-sums regrouped via LDS:
// part2[256j+t] = sum of pixels 4t+1024j..+3  ==  part2[16h+c4] = quad (h,c4).
//   xsum[g]  = part2[16(g>>2)+4(g&3) .. +3]        (16 consecutive pixels)
//   xavg[n]  = mean of part2[(4bh+i)*16+bw], i=0..3 (4x4 spatial block)
// Blocks 4096..4479: Wq|Wk|Wv fp32->bf16 (coalesced float4 pairs f, f+256).
// ---------------------------------------------------------------------------
__global__ void prep_kernel(const float* __restrict__ x,
                            const float* __restrict__ Wq,
                            const float* __restrict__ Wk,
                            const float* __restrict__ Wv,
                            unsigned short* __restrict__ xavg,
                            unsigned short* __restrict__ xsum,
                            unsigned short* __restrict__ Wb)
{
    const int blk = blockIdx.x;
    const int t = threadIdx.x;
    if (blk >= 4096) {                      // weight conversion
        const int f = (blk - 4096) * 512 + t;   // float4 id; pair (f, f+256)
        const int m = f >> 16;                  // 65536 float4 per matrix
        const int o = f & 65535;
        const float4* s4 = (const float4*)((m == 0) ? Wq : (m == 1) ? Wk : Wv);
        float4 a = s4[o];
        float4 b = s4[o + 256];
        ushort4* d4 = (ushort4*)(Wb + (size_t)m * 262144);
        d4[o]       = make_ushort4(f2bf(a.x), f2bf(a.y), f2bf(a.z), f2bf(a.w));
        d4[o + 256] = make_ushort4(f2bf(b.x), f2bf(b.y), f2bf(b.z), f2bf(b.w));
        return;
    }
    const int b = blk >> 9;                 // plane = b*512 + c
    const int c = blk & 511;

    const float4* x4 = (const float4*)(x + (size_t)blk * 4096);
    float4 f0 = x4[t], f1 = x4[t + 256], f2 = x4[t + 512], f3 = x4[t + 768];

    __shared__ float part2[1024];
    part2[t]       = f0.x + f0.y + f0.z + f0.w;
    part2[t + 256] = f1.x + f1.y + f1.z + f1.w;
    part2[t + 512] = f2.x + f2.y + f2.z + f2.w;
    part2[t + 768] = f3.x + f3.y + f3.z + f3.w;
    __syncthreads();

    // xsum: group g = t (16 consecutive flat pixels)
    {
        const int base = 16 * (t >> 2) + 4 * (t & 3);
        float4 q = *(const float4*)&part2[base];
        xsum[((size_t)b * 256 + t) * 512 + c] = f2bf(q.x + q.y + q.z + q.w);
    }
    // xavg: spatial block n = t = bh*16+bw
    {
        const int bh = t >> 4, bw = t & 15;
        float m = (part2[(bh * 4 + 0) * 16 + bw] + part2[(bh * 4 + 1) * 16 + bw] +
                   part2[(bh * 4 + 2) * 16 + bw] + part2[(bh * 4 + 3) * 16 + bw]) * 0.0625f;
        xavg[((size_t)b * 256 + t) * 512 + c] = f2bf(m);
    }
}

// ---------------------------------------------------------------------------
// K2: joint projection (384 blocks). 32x64 tile/wave, 6 loads -> 8 MFMAs.
// Blocks 0..255:  QK[2048x1024] = xavg @ [Wq;Wk]^T + [bq;bk].
// Blocks 256..383: VsT[b][c][m] = (xsum[b] @ Wv^T + 16*bv)^T.
// ---------------------------------------------------------------------------
__global__ void __launch_bounds__(256, 2)
proj_gemm(const unsigned short* __restrict__ xavg,
          const unsigned short* __restrict__ xsum,
          const unsigned short* __restrict__ Wb,
          const float* __restrict__ bq,
          const float* __restrict__ bk,
          const float* __restrict__ bv,
          unsigned short* __restrict__ QK,
          unsigned short* __restrict__ VsT)
{
    const int blk = blockIdx.x;
    const int lane = threadIdx.x & 63, quad = lane >> 4, r16 = lane & 15;
    const int w = threadIdx.x >> 6;

    if (blk < 256) {                        // ---- QK projection ----
        const int wave = blk * 4 + w;       // 0..1023
        const int mt2 = wave >> 4;          // 0..63 (32-row tiles)
        const int nt4 = wave & 15;          // 0..15 (64-col tiles)
        const unsigned short* xp0 = xavg + (size_t)(mt2 * 32 + r16) * 512 + quad * 8;
        const unsigned short* xp1 = xp0 + 16 * 512;
        const unsigned short* wp0 = Wb + (size_t)(nt4 * 64 + r16) * 512 + quad * 8;
        const unsigned short* wp1 = wp0 + 16 * 512;
        const unsigned short* wp2 = wp0 + 32 * 512;
        const unsigned short* wp3 = wp0 + 48 * 512;

        f32x4 a00 = {0,0,0,0}, a01 = a00, a02 = a00, a03 = a00;
        f32x4 a10 = a00, a11 = a00, a12 = a00, a13 = a00;
#pragma unroll 4
        for (int k = 0; k < 512; k += 32) {
            short8 qa0 = *(const short8*)(xp0 + k);
            short8 qa1 = *(const short8*)(xp1 + k);
            short8 b0 = *(const short8*)(wp0 + k);
            short8 b1 = *(const short8*)(wp1 + k);
            short8 b2 = *(const short8*)(wp2 + k);
            short8 b3 = *(const short8*)(wp3 + k);
            a00 = mfma16(qa0, b0, a00); a01 = mfma16(qa0, b1, a01);
            a02 = mfma16(qa0, b2, a02); a03 = mfma16(qa0, b3, a03);
            a10 = mfma16(qa1, b0, a10); a11 = mfma16(qa1, b1, a11);
            a12 = mfma16(qa1, b2, a12); a13 = mfma16(qa1, b3, a13);
        }
        const int row0 = mt2 * 32 + quad * 4;
        f32x4 accs0[4] = {a00, a01, a02, a03};
        f32x4 accs1[4] = {a10, a11, a12, a13};
#pragma unroll
        for (int j = 0; j < 4; ++j) {
            const int c = nt4 * 64 + j * 16 + r16;
            const float bias = (c < 512) ? bq[c] : bk[c - 512];
#pragma unroll
            for (int r = 0; r < 4; ++r) {
                QK[(size_t)(row0 + r) * 1024 + c]      = f2bf(accs0[j][r] + bias);
                QK[(size_t)(row0 + 16 + r) * 1024 + c] = f2bf(accs1[j][r] + bias);
            }
        }
    } else {                                // ---- V projection (transposed) ----
        const int vblk = blk - 256;         // 0..127
        const int b = vblk >> 4;            // 0..7
        const int wave = (vblk & 15) * 4 + w;   // 0..63
        const int mt2 = wave >> 3;          // 0..7
        const int nt4 = wave & 7;           // 0..7
        const unsigned short* xp0 = xsum + (size_t)b * 131072 + (size_t)(mt2 * 32 + r16) * 512 + quad * 8;
        const unsigned short* xp1 = xp0 + 16 * 512;
        const unsigned short* wp0 = Wb + 524288 + (size_t)(nt4 * 64 + r16) * 512 + quad * 8;
        const unsigned short* wp1 = wp0 + 16 * 512;
        const unsigned short* wp2 = wp0 + 32 * 512;
        const unsigned short* wp3 = wp0 + 48 * 512;

        f32x4 a00 = {0,0,0,0}, a01 = a00, a02 = a00, a03 = a00;
        f32x4 a10 = a00, a11 = a00, a12 = a00, a13 = a00;
#pragma unroll 4
        for (int k = 0; k < 512; k += 32) {
            short8 qa0 = *(const short8*)(xp0 + k);
            short8 qa1 = *(const short8*)(xp1 + k);
            short8 b0 = *(const short8*)(wp0 + k);
            short8 b1 = *(const short8*)(wp1 + k);
            short8 b2 = *(const short8*)(wp2 + k);
            short8 b3 = *(const short8*)(wp3 + k);
            a00 = mfma16(qa0, b0, a00); a01 = mfma16(qa0, b1, a01);
            a02 = mfma16(qa0, b2, a02); a03 = mfma16(qa0, b3, a03);
            a10 = mfma16(qa1, b0, a10); a11 = mfma16(qa1, b1, a11);
            a12 = mfma16(qa1, b2, a12); a13 = mfma16(qa1, b3, a13);
        }
        unsigned short* vb = VsT + (size_t)b * 131072;
        const int m0 = mt2 * 32 + quad * 4;
        f32x4 accs0[4] = {a00, a01, a02, a03};
        f32x4 accs1[4] = {a10, a11, a12, a13};
#pragma unroll
        for (int j = 0; j < 4; ++j) {
            const int c = nt4 * 64 + j * 16 + r16;
            const float bias = 16.f * bv[c];
#pragma unroll
            for (int r = 0; r < 4; ++r) {
                vb[(size_t)c * 256 + m0 + r]      = f2bf(accs0[j][r] + bias);
                vb[(size_t)c * 256 + m0 + 16 + r] = f2bf(accs1[j][r] + bias);
            }
        }
    }
}

// ---------------------------------------------------------------------------
// K3: scores + softmax, 16-row strips (128 blocks: 16 strips x 8 batches).
// 4 waves: each computes 16 rows x 64 cols (K=512, 5 loads -> 4 MFMAs) into
// LDS S; softmax with 16 threads/row -> bf16 Amat (coalesced 512 B rows).
// ---------------------------------------------------------------------------
__global__ void __launch_bounds__(256, 2)
score_softmax(const unsigned short* __restrict__ QK,
              unsigned short* __restrict__ Amat)
{
    __shared__ float S[16][257];
    const int b = blockIdx.y, strip = blockIdx.x;   // strip: 0..15
    const int w = threadIdx.x >> 6, lane = threadIdx.x & 63;
    const int quad = lane >> 4, r16 = lane & 15;

    {
        const unsigned short* qp = QK + (size_t)(b * 256 + strip * 16 + r16) * 1024 + quad * 8;
        const unsigned short* kp0 = QK + (size_t)(b * 256 + w * 64 + r16) * 1024 + 512 + quad * 8;
        const unsigned short* kp1 = kp0 + 16 * 1024;
        const unsigned short* kp2 = kp0 + 32 * 1024;
        const unsigned short* kp3 = kp0 + 48 * 1024;

        f32x4 a0 = {0,0,0,0}, a1 = a0, a2 = a0, a3 = a0;
#pragma unroll 4
        for (int k = 0; k < 512; k += 32) {
            short8 qa = *(const short8*)(qp + k);
            short8 b0 = *(const short8*)(kp0 + k);
            short8 b1 = *(const short8*)(kp1 + k);
            short8 b2 = *(const short8*)(kp2 + k);
            short8 b3 = *(const short8*)(kp3 + k);
            a0 = mfma16(qa, b0, a0); a1 = mfma16(qa, b1, a1);
            a2 = mfma16(qa, b2, a2); a3 = mfma16(qa, b3, a3);
        }
        f32x4 accs[4] = {a0, a1, a2, a3};
#pragma unroll
        for (int j = 0; j < 4; ++j) {
            const int col = w * 64 + j * 16 + r16;
#pragma unroll
            for (int r = 0; r < 4; ++r)
                S[quad * 4 + r][col] = accs[j][r];
        }
    }
    __syncthreads();

    {
        const int t = threadIdx.x;
        const int r = t >> 4, idx = t & 15;     // row r, cols idx*16..+15
        float v[16];
        float mx = -3.4e38f;
#pragma unroll
        for (int j = 0; j < 16; ++j) {
            v[j] = S[r][idx * 16 + j] * 0.044194173824159216f;
            mx = fmaxf(mx, v[j]);
        }
        mx = fmaxf(mx, __shfl_xor(mx, 1));
        mx = fmaxf(mx, __shfl_xor(mx, 2));
        mx = fmaxf(mx, __shfl_xor(mx, 4));
        mx = fmaxf(mx, __shfl_xor(mx, 8));
        float sum = 0.f;
#pragma unroll
        for (int j = 0; j < 16; ++j) { v[j] = __expf(v[j] - mx); sum += v[j]; }
        sum += __shfl_xor(sum, 1);
        sum += __shfl_xor(sum, 2);
        sum += __shfl_xor(sum, 4);
        sum += __shfl_xor(sum, 8);
        const float inv = 1.f / sum;
        unsigned short* ap = Amat + (size_t)b * 65536 + (size_t)(strip * 16 + r) * 256 + idx * 16;
#pragma unroll
        for (int j = 0; j < 16; j += 4)
            *(ushort4*)(ap + j) = make_ushort4(f2bf(v[j] * inv), f2bf(v[j + 1] * inv),
                                               f2bf(v[j + 2] * inv), f2bf(v[j + 3] * inv));
    }
}

// ---------------------------------------------------------------------------
// K4: out = expand16(A @ Vsum). Grid (16 half-strips x 8 c-eighths, 8 b) =
// 1024 blocks, 4 blocks/CU (LDS 4.4 KB), 16 waves/CU. One 16x16 tile/wave,
// K=256 fully unrolled, frags direct from global. Transpose via tiny LDS,
// then fully-coalesced 64 MiB write (1 KB contiguous per wave instruction).
// ---------------------------------------------------------------------------
__global__ void __launch_bounds__(256, 4)
av_expand(const unsigned short* __restrict__ Amat,
          const unsigned short* __restrict__ VsT,
          float* __restrict__ out)
{
    __shared__ float osT[64][17];           // [local ch][local n]
    const int b = blockIdx.y;
    const int sh = blockIdx.x >> 3;         // 0..15: 16-row half-strip
    const int cq = blockIdx.x & 7;          // 0..7: 64-channel group
    const int w = threadIdx.x >> 6, lane = threadIdx.x & 63;
    const int quad = lane >> 4, r16 = lane & 15;

    {
        const unsigned short* ap = Amat + (size_t)b * 65536 + (size_t)(sh * 16 + r16) * 256 + quad * 8;
        const unsigned short* vp = VsT + (size_t)b * 131072 +
                                   (size_t)(cq * 64 + w * 16 + r16) * 256 + quad * 8;
        f32x4 acc = {0.f, 0.f, 0.f, 0.f};
#pragma unroll
        for (int k = 0; k < 256; k += 32) {
            short8 a0 = *(const short8*)(ap + k);
            short8 b0 = *(const short8*)(vp + k);
            acc = mfma16(a0, b0, acc);
        }
#pragma unroll
        for (int r = 0; r < 4; ++r)
            osT[w * 16 + r16][quad * 4 + r] = acc[r];
    }
    __syncthreads();

    {
        const int t = threadIdx.x;
        const int ch4 = t >> 6;             // wave index: ch = it*4 + ch4
        const int j = t & 63;               // float4 index within channel
        const int n = j >> 2;               // local block-row 0..15
        float* obase = out + (size_t)(b * 512 + cq * 64) * 4096 + sh * 256 + j * 4;
#pragma unroll
        for (int it = 0; it < 16; ++it) {
            const int ch = it * 4 + ch4;
            const float v = osT[ch][n];
            *(float4*)(obase + (size_t)ch * 4096) = make_float4(v, v, v, v);
        }
    }
}

extern "C" void kernel_launch(void* const* d_in, const int* in_sizes, int n_in,
                              void* d_out, int out_size, void* d_ws, size_t ws_size,
                              hipStream_t stream) {
    const float* x  = (const float*)d_in[0];
    const float* Wq = (const float*)d_in[1];
    const float* bq = (const float*)d_in[2];
    const float* Wk = (const float*)d_in[3];
    const float* bk = (const float*)d_in[4];
    const float* Wv = (const float*)d_in[5];
    const float* bv = (const float*)d_in[6];
    float* out = (float*)d_out;

    // All scratch in d_ws (13 MB); fully written before read each call.
    // d_out written exactly once (by av_expand).
    unsigned short* Wb   = (unsigned short*)d_ws;    // 786432 shorts (Wq|Wk|Wv)
    unsigned short* xavg = Wb + 786432;              // 1048576
    unsigned short* xsum = xavg + 1048576;           // 1048576
    unsigned short* QK   = xsum + 1048576;           // 2097152 (2048x1024)
    unsigned short* VsT  = QK + 2097152;             // 1048576 (8 x 512x256)
    unsigned short* Amat = VsT + 1048576;            // 524288  (8 x 256x256)

    // K1: plane reductions (4096 blocks) + weight convert (384 blocks)
    prep_kernel<<<4480, 256, 0, stream>>>(x, Wq, Wk, Wv, xavg, xsum, Wb);
    // K2: QK = xavg @ [Wq;Wk]^T + bias  AND  VsT = (xsum @ Wv^T + 16*bv)^T
    proj_gemm<<<384, 256, 0, stream>>>(xavg, xsum, Wb, bq, bk, bv, QK, VsT);
    // K3: A = softmax(QK^T/sqrt(512)) once per 16-row strip -> Amat (d_ws)
    score_softmax<<<dim3(16, 8), 256, 0, stream>>>(QK, Amat);
    // K4: out = expand16(A @ Vsum), write-bound, high occupancy
    av_expand<<<dim3(128, 8), 256, 0, stream>>>(Amat, VsT, out);
}